// Round 8
// baseline (704.414 us; speedup 1.0000x reference)
//
#include <hip/hip_runtime.h>
#include <math.h>

#define B_ 4
#define N_ 5000
#define K_ 16
#define L_ 3
#define F_ 2
#define E_ 32
#define D_ 64
#define H_ 4
#define BN_ (B_*N_)          /* 20000 */
#define NK_ (N_*K_)          /* 80000 */
#define BIG_ 1.0e9f
#define PD_ 65               /* padded LDS tile row stride (floats) */

// ---------------- zero the accumulators -------------------------------------
__global__ void k_zero(float* __restrict__ acc) {
    if (threadIdx.x < 192) acc[threadIdx.x] = 0.f;
}

// ---------------- encoder: h = [emb_norm, feat] @ enc_W + enc_b -------------
__global__ __launch_bounds__(256) void k_encode(
    const float* __restrict__ embed, const float* __restrict__ feat,
    const float* __restrict__ encW, const float* __restrict__ encb,
    float* __restrict__ h)
{
    int wave = threadIdx.x >> 6;
    int lane = threadIdx.x & 63;
    int node = blockIdx.x * 4 + wave;      // b*N+n  in [0,20000)
    int n = node % N_;

    float e = (lane < E_) ? embed[(size_t)n * E_ + lane] : 0.f;
    float ss = e * e;
    #pragma unroll
    for (int m = 32; m >= 1; m >>= 1) ss += __shfl_xor(ss, m, 64);
    float scale = 1.f / fmaxf(sqrtf(ss), 1.f);

    float inval = (lane < E_) ? e * scale
                : (lane < E_ + F_) ? feat[(size_t)node * F_ + (lane - E_)]
                : 0.f;

    float acc = encb[lane];
    #pragma unroll
    for (int i = 0; i < E_ + F_; ++i)
        acc = fmaf(__shfl(inval, i, 64), encW[i * D_ + lane], acc);
    h[(size_t)node * D_ + lane] = acc;
}

// ---- 4-row x 4-col register-tile GEMM: A tile (LDS, pad PD_), W (LDS 64x64)
__device__ __forceinline__ void mm4(
    const float* T, const float* W, int r0, int c0, float acc[4][4])
{
    #pragma unroll 2
    for (int i = 0; i < 64; i += 4) {
        float4 a[4];
        #pragma unroll
        for (int k = 0; k < 4; ++k) a[k] = *(const float4*)&T[(r0 + k) * PD_ + i];
        #pragma unroll
        for (int ii = 0; ii < 4; ++ii) {
            float4 w = *(const float4*)&W[(i + ii) * 64 + c0];
            #pragma unroll
            for (int k = 0; k < 4; ++k) {
                float av = (ii == 0) ? a[k].x : (ii == 1) ? a[k].y
                         : (ii == 2) ? a[k].z : a[k].w;
                acc[k][0] = fmaf(av, w.x, acc[k][0]);
                acc[k][1] = fmaf(av, w.y, acc[k][1]);
                acc[k][2] = fmaf(av, w.z, acc[k][2]);
                acc[k][3] = fmaf(av, w.w, acc[k][3]);
            }
        }
    }
}

// cooperative 16KB weight stage: global -> LDS (128 threads)
__device__ __forceinline__ void stageW(float* dst, const float* __restrict__ src, int tx)
{
    #pragma unroll
    for (int i = tx; i < 1024; i += 128)
        ((float4*)dst)[i] = ((const float4*)src)[i];
}

// ================= fully fused graph layer (4x4 register tiles) =============
// 32 nodes/block, 128 threads: thread = (rg = tx>>4 -> rows rg*4..+3,
// cg = tx&15 -> cols cg*4..+3). Tiles are row-group-local (16 lanes of one
// wave own a row) -> barriers ONLY around single-slot W staging.
__global__ __launch_bounds__(128) void k_layer(
    const float* __restrict__ hin, float* __restrict__ hout,
    const int* __restrict__ neigh, const int* __restrict__ numn,
    const float* __restrict__ nbW, const float* __restrict__ Wq,
    const float* __restrict__ Wk, const float* __restrict__ Wv,
    const float* __restrict__ Wo,
    const float* __restrict__ gWz, const float* __restrict__ gUz, const float* __restrict__ gbz,
    const float* __restrict__ gWr, const float* __restrict__ gUr, const float* __restrict__ gbr,
    const float* __restrict__ gWh, const float* __restrict__ gUh, const float* __restrict__ gbh)
{
    __shared__ float sW[64 * 64];          // 16KB single W slot
    __shared__ float tH[32 * PD_];         // h tile
    __shared__ float tS0[32 * PD_];        // states0 -> ao -> x
    __shared__ float tS1[32 * PD_];        // states1 -> rh
    __shared__ float tS2[32 * PD_];        // states2

    int tx = threadIdx.x;
    int rg = tx >> 4, cg = tx & 15;
    int r0 = rg * 4, c0 = cg * 4;
    int base = blockIdx.x * 32;            // grid exact: 625*32 = 20000

    // ---- P0: stage Wq, load h rows ----
    stageW(sW, Wq, tx);
    #pragma unroll
    for (int k = 0; k < 4; ++k)
        *(float4*)&tH[(r0 + k) * PD_ + c0] =
            *(const float4*)&hin[(size_t)(base + r0 + k) * 64 + c0];
    __syncthreads();

    float qv[4][4] = {};
    mm4(tH, sW, r0, c0, qv);

    // ---- P1: nbW; gather-mean + states per t ----
    __syncthreads();
    stageW(sW, nbW, tx);
    __syncthreads();

    float* tS[3] = {tS0, tS1, tS2};
    #pragma unroll
    for (int t = 0; t < 3; ++t) {
        #pragma unroll
        for (int k = 0; k < 4; ++k) {
            int g = base + r0 + k;
            int bb = g / N_;
            int padv = numn[bb];
            const float4* hb4 = (const float4*)(hin + (size_t)bb * N_ * D_);
            const int* nb = neigh + ((size_t)t * BN_ + g) * K_;
            float sx = 0.f, sy = 0.f, sz = 0.f, sw = 0.f;
            int cnt = 0;
            #pragma unroll
            for (int kk = 0; kk < K_; ++kk) {
                int idx = nb[kk];
                if (idx != padv) {
                    float4 v = hb4[(size_t)idx * 16 + cg];
                    sx += v.x; sy += v.y; sz += v.z; sw += v.w;
                    cnt++;
                }
            }
            float inv = 1.f / fmaxf((float)cnt, 1.f);
            *(float4*)&tS[t][(r0 + k) * PD_ + c0] =
                make_float4(sx * inv, sy * inv, sz * inv, sw * inv);
        }
        float sr[4][4] = {};
        mm4(tS[t], sW, r0, c0, sr);        // mean @ nbW (in-place safe: row-group lockstep)
        #pragma unroll
        for (int k = 0; k < 4; ++k)
            *(float4*)&tS[t][(r0 + k) * PD_ + c0] =
                make_float4(tanhf(sr[k][0]), tanhf(sr[k][1]),
                            tanhf(sr[k][2]), tanhf(sr[k][3]));
    }

    // ---- P2: Wk; scores ----
    __syncthreads();
    stageW(sW, Wk, tx);
    __syncthreads();
    float p[3][4];
    #pragma unroll
    for (int t = 0; t < 3; ++t) {
        float ak[4][4] = {};
        mm4(tS[t], sW, r0, c0, ak);
        #pragma unroll
        for (int k = 0; k < 4; ++k) {
            float pp = ak[k][0] * qv[k][0] + ak[k][1] * qv[k][1]
                     + ak[k][2] * qv[k][2] + ak[k][3] * qv[k][3];
            pp += __shfl_xor(pp, 1, 64);   // reduce over the 4 col-threads of a head
            pp += __shfl_xor(pp, 2, 64);
            p[t][k] = pp * 0.25f;          // / sqrt(dh=16)
        }
    }

    // ---- P3: Wv; vv in regs; softmax; ao -> tS0 ----
    __syncthreads();
    stageW(sW, Wv, tx);
    __syncthreads();
    float av[3][4][4];
    #pragma unroll
    for (int t = 0; t < 3; ++t) {
        #pragma unroll
        for (int k = 0; k < 4; ++k)
            #pragma unroll
            for (int j = 0; j < 4; ++j) av[t][k][j] = 0.f;
        mm4(tS[t], sW, r0, c0, av[t]);
    }
    #pragma unroll
    for (int k = 0; k < 4; ++k) {
        float mx = fmaxf(p[0][k], fmaxf(p[1][k], p[2][k]));
        float e0 = expf(p[0][k] - mx), e1 = expf(p[1][k] - mx), e2 = expf(p[2][k] - mx);
        float winv = 1.f / (e0 + e1 + e2);
        float w0 = e0 * winv, w1 = e1 * winv, w2 = e2 * winv;
        *(float4*)&tS0[(r0 + k) * PD_ + c0] = make_float4(
            w0 * av[0][k][0] + w1 * av[1][k][0] + w2 * av[2][k][0],
            w0 * av[0][k][1] + w1 * av[1][k][1] + w2 * av[2][k][1],
            w0 * av[0][k][2] + w1 * av[1][k][2] + w2 * av[2][k][2],
            w0 * av[0][k][3] + w1 * av[1][k][3] + w2 * av[2][k][3]);
    }

    // ---- P4: Wo; x = tanh(ao@Wo) in-place tS0 ----
    __syncthreads();
    stageW(sW, Wo, tx);
    __syncthreads();
    {
        float xr[4][4] = {};
        mm4(tS0, sW, r0, c0, xr);
        #pragma unroll
        for (int k = 0; k < 4; ++k)
            *(float4*)&tS0[(r0 + k) * PD_ + c0] =
                make_float4(tanhf(xr[k][0]), tanhf(xr[k][1]),
                            tanhf(xr[k][2]), tanhf(xr[k][3]));
    }

    // ---- GRU: z/r gates ----
    float az[4][4] = {}, ar[4][4] = {};
    __syncthreads(); stageW(sW, gWz, tx); __syncthreads();
    mm4(tS0, sW, r0, c0, az);
    __syncthreads(); stageW(sW, gUz, tx); __syncthreads();
    mm4(tH, sW, r0, c0, az);
    __syncthreads(); stageW(sW, gWr, tx); __syncthreads();
    mm4(tS0, sW, r0, c0, ar);
    __syncthreads(); stageW(sW, gUr, tx); __syncthreads();
    mm4(tH, sW, r0, c0, ar);

    float4 bzv = *(const float4*)&gbz[c0];
    float4 brv = *(const float4*)&gbr[c0];
    float z[4][4];
    #pragma unroll
    for (int k = 0; k < 4; ++k) {
        float bzs[4] = {bzv.x, bzv.y, bzv.z, bzv.w};
        float brs[4] = {brv.x, brv.y, brv.z, brv.w};
        float4 hv = *(const float4*)&tH[(r0 + k) * PD_ + c0];
        float hs[4] = {hv.x, hv.y, hv.z, hv.w};
        float rh[4];
        #pragma unroll
        for (int j = 0; j < 4; ++j) {
            z[k][j] = 1.f / (1.f + expf(-(az[k][j] + bzs[j])));
            float rrv = 1.f / (1.f + expf(-(ar[k][j] + brs[j])));
            rh[j] = rrv * hs[j];
        }
        *(float4*)&tS1[(r0 + k) * PD_ + c0] = make_float4(rh[0], rh[1], rh[2], rh[3]);
    }

    float ah[4][4] = {};
    __syncthreads(); stageW(sW, gWh, tx); __syncthreads();
    mm4(tS0, sW, r0, c0, ah);
    __syncthreads(); stageW(sW, gUh, tx); __syncthreads();
    mm4(tS1, sW, r0, c0, ah);

    float4 bhv = *(const float4*)&gbh[c0];
    #pragma unroll
    for (int k = 0; k < 4; ++k) {
        float bhs[4] = {bhv.x, bhv.y, bhv.z, bhv.w};
        float4 hv = *(const float4*)&tH[(r0 + k) * PD_ + c0];
        float hs[4] = {hv.x, hv.y, hv.z, hv.w};
        float o[4];
        #pragma unroll
        for (int j = 0; j < 4; ++j) {
            float hh = tanhf(ah[k][j] + bhs[j]);
            o[j] = (1.f - z[k][j]) * hs[j] + z[k][j] * hh;
        }
        *(float4*)&hout[(size_t)(base + r0 + k) * 64 + c0] =
            make_float4(o[0], o[1], o[2], o[3]);
    }
}

// ---------------- edge projection ------------------------------------------
__global__ __launch_bounds__(256) void k_edgeproj(
    const float* __restrict__ h, const float* __restrict__ W1,
    float* __restrict__ P)
{
    int wave = threadIdx.x >> 6;
    int lane = threadIdx.x & 63;
    int node = blockIdx.x * 4 + wave;      // < 20000

    float hval = h[(size_t)node * D_ + lane];
    const float* wp = (lane < 32) ? (W1 + lane) : (W1 + 64 * 32 + (lane - 32));
    float acc = 0.f;
    #pragma unroll 8
    for (int i = 0; i < D_; ++i)
        acc = fmaf(__shfl(hval, i, 64), wp[i * 32], acc);
    P[(size_t)node * D_ + lane] = acc;
}

// ---------------- edge decoder (light) --------------------------------------
__global__ __launch_bounds__(256) void k_decoder2(
    const float* __restrict__ P, const int* __restrict__ adj,
    const float* __restrict__ b1, const float* __restrict__ W2,
    const float* __restrict__ b2, const int* __restrict__ num_nodes,
    float* __restrict__ nw)
{
    int half = threadIdx.x >> 5;   // 0..7
    int j    = threadIdx.x & 31;
    float bias = b1[j], w2 = W2[j], b2v = b2[0];

    #pragma unroll 1
    for (int p = 0; p < 16; ++p) {
        int e = blockIdx.x * 128 + p * 8 + half;  // edge id < 320000
        int node = e >> 4;                        // b*N+n
        int b = node / N_;
        int a = adj[e];
        int pad = num_nodes[b];
        float own = P[(size_t)node * D_ + j];
        bool pd = (a == pad);
        float nbr = pd ? 0.f : P[((size_t)b * N_ + a) * D_ + 32 + j];
        float am = pd ? 0.f : 1.f;
        float t = tanhf(bias + am * own + nbr);
        float part = t * w2;
        #pragma unroll
        for (int m = 1; m < 32; m <<= 1) part += __shfl_xor(part, m, 64);
        if (j == 0) nw[e] = part + b2v;
    }
}

// ---------------- dual vars (per node scalar) + dual_demand -----------------
__global__ __launch_bounds__(256) void k_dualvars(
    const float* __restrict__ h, const float* __restrict__ W1,
    const float* __restrict__ b1, const float* __restrict__ W2,
    const float* __restrict__ b2, const float* __restrict__ demands,
    const int* __restrict__ num_nodes,
    float* __restrict__ dv, float* __restrict__ acc_out)
{
    __shared__ float sW1[D_ * 32];
    __shared__ float sW2[32];
    __shared__ float sPart[8];
    for (int i = threadIdx.x; i < D_ * 32; i += 256) sW1[i] = W1[i];
    if (threadIdx.x < 32) sW2[threadIdx.x] = W2[threadIdx.x];
    __syncthreads();

    int half = threadIdx.x >> 5;
    int j    = threadIdx.x & 31;
    int b = (blockIdx.x * 40) / N_;
    float bias = b1[j], b2v = b2[0];
    float local = 0.f;

    #pragma unroll 1
    for (int p = 0; p < 5; ++p) {
        int node = blockIdx.x * 40 + p * 8 + half;    // < 20000
        const float* hp = h + (size_t)node * D_;
        float h0 = hp[j], h1 = hp[j + 32];
        float acc = bias;
        #pragma unroll 8
        for (int i = 0; i < 32; ++i) {
            acc = fmaf(__shfl(h0, i, 32), sW1[i * 32 + j],        acc);
            acc = fmaf(__shfl(h1, i, 32), sW1[(i + 32) * 32 + j], acc);
        }
        float t = tanhf(acc);
        float part = t * sW2[j];
        #pragma unroll
        for (int m = 1; m < 32; m <<= 1) part += __shfl_xor(part, m, 64);
        if (j == 0) {
            float v = part + b2v;
            dv[node] = v;
            local += v * demands[node];
        }
    }
    if (j == 0) sPart[half] = local;
    __syncthreads();
    if (threadIdx.x == 0) {
        float s = 0.f;
        #pragma unroll
        for (int i = 0; i < 8; ++i) s += sPart[i];
        atomicAdd(&acc_out[(b * 3 + 2) * 16], s);
    }
}

// ---------------- dest softmax over permuted groups -------------------------
__global__ void k_dest(
    const float* __restrict__ nw, const int* __restrict__ in_idx,
    const int* __restrict__ inv_adj, const int* __restrict__ num_nodes,
    float* __restrict__ dest)
{
    int t = blockIdx.x * 256 + threadIdx.x;
    if (t >= BN_) return;
    int b = t / N_;
    int pad = num_nodes[b];
    float vals[K_]; float mx = -INFINITY;
    #pragma unroll
    for (int k = 0; k < K_; ++k) {
        int jj = in_idx[(size_t)t * K_ + k];
        float g = nw[(size_t)b * NK_ + jj];
        float im = (inv_adj[(size_t)t * K_ + k] == pad) ? 1.f : 0.f;
        float v = g - BIG_ * im;
        vals[k] = v; mx = fmaxf(mx, v);
    }
    float s = 0.f;
    #pragma unroll
    for (int k = 0; k < K_; ++k) { vals[k] = expf(vals[k] - mx); s += vals[k]; }
    float invs = 1.f / s;
    #pragma unroll
    for (int k = 0; k < K_; ++k) dest[(size_t)t * K_ + k] = vals[k] * invs;
}

// ---------------- normalized_weights + flow0 --------------------------------
__global__ void k_normw(
    const float* __restrict__ nw, const float* __restrict__ dest,
    const int* __restrict__ rev, const int* __restrict__ adj,
    const int* __restrict__ num_nodes, const float* __restrict__ demands,
    float* __restrict__ normw, float* __restrict__ flow0)
{
    int t = blockIdx.x * 256 + threadIdx.x;
    if (t >= BN_) return;
    int b = t / N_;
    int pad = num_nodes[b];
    float vals[K_]; float mx = -INFINITY;
    #pragma unroll
    for (int k = 0; k < K_; ++k) {
        size_t e = (size_t)t * K_ + k;
        float v = nw[e] * dest[(size_t)b * NK_ + rev[e]];
        float m = (adj[e] == pad) ? 1.f : 0.f;
        v -= BIG_ * m;
        vals[k] = v; mx = fmaxf(mx, v);
    }
    float s = 0.f;
    #pragma unroll
    for (int k = 0; k < K_; ++k) { vals[k] = expf(vals[k] - mx); s += vals[k]; }
    float invs = 1.f / s;
    float supply = fmaxf(-demands[t], 0.f);
    #pragma unroll
    for (int k = 0; k < K_; ++k) {
        float w = vals[k] * invs;
        normw[(size_t)t * K_ + k] = w;
        flow0[(size_t)t * K_ + k] = w * supply;
    }
}

// ---------------- one MCF flow step -----------------------------------------
__global__ void k_flow(
    const float* __restrict__ cur, const float* __restrict__ normw,
    const int* __restrict__ in_idx, const int* __restrict__ inv_adj,
    const int* __restrict__ num_nodes, const float* __restrict__ demands,
    float* __restrict__ nxt)
{
    int t = blockIdx.x * 256 + threadIdx.x;
    if (t >= BN_) return;
    int b = t / N_;
    int pad = num_nodes[b];
    float inflow = 0.f;
    #pragma unroll
    for (int k = 0; k < K_; ++k) {
        size_t e = (size_t)t * K_ + k;
        if (inv_adj[e] != pad) inflow += cur[(size_t)b * NK_ + in_idx[e]];
    }
    float tot = inflow + fmaxf(-demands[t], 0.f);
    #pragma unroll
    for (int k = 0; k < K_; ++k)
        nxt[(size_t)t * K_ + k] = normw[(size_t)t * K_ + k] * tot;
}

// ---------------- dual iterations + both cost reductions (dd fused) ---------
__global__ __launch_bounds__(256) void k_dualred(
    const float* __restrict__ el, const float* __restrict__ dv,
    const int* __restrict__ adj, const int* __restrict__ num_nodes,
    const float* __restrict__ flow, float* __restrict__ acc_out)
{
    int b = blockIdx.y;
    int ein = blockIdx.x * 256 + threadIdx.x;
    float c0 = 0.f, c1 = 0.f;
    if (ein < NK_) {
        size_t e = (size_t)b * NK_ + ein;
        int pad = num_nodes[b];
        int node = b * N_ + (ein >> 4);
        int a = adj[e];
        float am = (a == pad) ? 0.f : 1.f;
        float dtr = (a == pad) ? 0.f : dv[(size_t)b * N_ + a];
        float d = dtr - am * dv[node];
        float l = el[e];
        float f = 0.f, ac = 0.f;
        #pragma unroll
        for (int it = 0; it < 10; ++it) {
            float g = 2.f * l * f + d;
            ac = 0.9f * ac + 0.01f * g;
            f = fmaxf(f - ac, 0.f) * am;
        }
        float fl = flow[e];
        c0 = l * fl * fl;          // flow_cost term
        c1 = l * f * f + d * f;    // dual flow term
    }
    #pragma unroll
    for (int m = 1; m < 64; m <<= 1) { c0 += __shfl_xor(c0, m, 64); c1 += __shfl_xor(c1, m, 64); }
    __shared__ float s0[4], s1[4];
    int wave = threadIdx.x >> 6, lane = threadIdx.x & 63;
    if (lane == 0) { s0[wave] = c0; s1[wave] = c1; }
    __syncthreads();
    if (threadIdx.x == 0) {
        atomicAdd(&acc_out[(b * 3 + 0) * 16], s0[0] + s0[1] + s0[2] + s0[3]);
        atomicAdd(&acc_out[(b * 3 + 1) * 16], s1[0] + s1[1] + s1[2] + s1[3]);
    }
}

// ---------------- finalize --------------------------------------------------
__global__ void k_final(const float* __restrict__ acc, float* __restrict__ out) {
    int b = threadIdx.x;
    if (b < B_)
        out[b] = acc[(b * 3 + 0) * 16] - acc[(b * 3 + 1) * 16] + acc[(b * 3 + 2) * 16];
}

extern "C" void kernel_launch(void* const* d_in, const int* in_sizes, int n_in,
                              void* d_out, int out_size, void* d_ws, size_t ws_size,
                              hipStream_t stream)
{
    const float* demands = (const float*)d_in[0];
    const float* feat    = (const float*)d_in[1];
    const float* el      = (const float*)d_in[2];
    const float* embed   = (const float*)d_in[3];
    const float* encW    = (const float*)d_in[4];
    const float* encb    = (const float*)d_in[5];
    const float* nbW     = (const float*)d_in[6];
    const float* Wq      = (const float*)d_in[7];
    const float* Wk      = (const float*)d_in[8];
    const float* Wv      = (const float*)d_in[9];
    const float* Wo      = (const float*)d_in[10];
    const float* gWz     = (const float*)d_in[11];
    const float* gUz     = (const float*)d_in[12];
    const float* gbz     = (const float*)d_in[13];
    const float* gWr     = (const float*)d_in[14];
    const float* gUr     = (const float*)d_in[15];
    const float* gbr     = (const float*)d_in[16];
    const float* gWh     = (const float*)d_in[17];
    const float* gUh     = (const float*)d_in[18];
    const float* gbh     = (const float*)d_in[19];
    const float* decW1   = (const float*)d_in[20];
    const float* decb1   = (const float*)d_in[21];
    const float* decW2   = (const float*)d_in[22];
    const float* decb2   = (const float*)d_in[23];
    const float* dualW1  = (const float*)d_in[24];
    const float* dualb1  = (const float*)d_in[25];
    const float* dualW2  = (const float*)d_in[26];
    const float* dualb2  = (const float*)d_in[27];
    const int* adj       = (const int*)d_in[28];
    const int* invadj    = (const int*)d_in[29];
    const int* neigh     = (const int*)d_in[30];
    const int* inidx     = (const int*)d_in[31];
    const int* revidx    = (const int*)d_in[32];
    const int* numn      = (const int*)d_in[33];

    // workspace (floats)
    float* ws    = (float*)d_ws;
    float* h0    = ws;                   // 1,280,000
    float* h1    = ws + 1280000;         // 1,280,000 (ping-pong; P after layers)
    float* fb    = ws + 2560000;         // flow region
    float* nw    = fb;                   // 320,000
    float* dest  = fb + 320000;          // 320,000
    float* normw = fb + 640000;          // 320,000
    float* flowA = fb + 960000;          // 320,000
    float* flowB = fb + 1280000;         // 320,000
    float* dv    = fb + 1600000;         // 20,000
    float* P     = h1;                   // reuse (h1 dead after layer 1)
    float* acc   = ws + 4200000;         // 192

    k_zero<<<1, 256, 0, stream>>>(acc);
    k_encode<<<BN_ / 4, 256, 0, stream>>>(embed, feat, encW, encb, h0);

    // layer 0: h0 -> h1 ; layer 1: h1 -> h0  (gathers must read pre-layer h)
    k_layer<<<BN_ / 32, 128, 0, stream>>>(h0, h1, neigh, numn, nbW, Wq, Wk, Wv, Wo,
                                          gWz, gUz, gbz, gWr, gUr, gbr, gWh, gUh, gbh);
    k_layer<<<BN_ / 32, 128, 0, stream>>>(h1, h0, neigh, numn, nbW, Wq, Wk, Wv, Wo,
                                          gWz, gUz, gbz, gWr, gUr, gbr, gWh, gUh, gbh);
    float* h = h0;

    k_edgeproj<<<BN_ / 4, 256, 0, stream>>>(h, decW1, P);
    k_decoder2<<<(B_ * NK_) / 128, 256, 0, stream>>>(P, adj, decb1, decW2, decb2, numn, nw);
    k_dualvars<<<BN_ / 40, 256, 0, stream>>>(h, dualW1, dualb1, dualW2, dualb2, demands, numn, dv, acc);
    k_dest<<<(BN_ + 255) / 256, 256, 0, stream>>>(nw, inidx, invadj, numn, dest);
    k_normw<<<(BN_ + 255) / 256, 256, 0, stream>>>(nw, dest, revidx, adj, numn, demands, normw, flowA);

    float* cur = flowA; float* nxt = flowB;
    for (int it = 0; it < 10; ++it) {
        k_flow<<<(BN_ + 255) / 256, 256, 0, stream>>>(cur, normw, inidx, invadj, numn, demands, nxt);
        float* tmp = cur; cur = nxt; nxt = tmp;
    }

    dim3 gred((NK_ + 255) / 256, B_);
    k_dualred<<<gred, 256, 0, stream>>>(el, dv, adj, numn, cur, acc);
    k_final<<<1, 64, 0, stream>>>(acc, (float*)d_out);
}

// Round 9
// 431.313 us; speedup vs baseline: 1.6332x; 1.6332x over previous
//
#include <hip/hip_runtime.h>
#include <math.h>

#define B_ 4
#define N_ 5000
#define K_ 16
#define L_ 3
#define F_ 2
#define E_ 32
#define D_ 64
#define H_ 4
#define BN_ (B_*N_)          /* 20000 */
#define NK_ (N_*K_)          /* 80000 */
#define BIG_ 1.0e9f
#define RS_ 68               /* padded LDS row stride (floats) */

// ---------------- zero the accumulators -------------------------------------
__global__ void k_zero(float* __restrict__ acc) {
    if (threadIdx.x < 192) acc[threadIdx.x] = 0.f;
}

// ---------------- encoder: h = [emb_norm, feat] @ enc_W + enc_b -------------
__global__ __launch_bounds__(256) void k_encode(
    const float* __restrict__ embed, const float* __restrict__ feat,
    const float* __restrict__ encW, const float* __restrict__ encb,
    float* __restrict__ h)
{
    int wave = threadIdx.x >> 6;
    int lane = threadIdx.x & 63;
    int node = blockIdx.x * 4 + wave;      // b*N+n  in [0,20000)
    int n = node % N_;

    float e = (lane < E_) ? embed[(size_t)n * E_ + lane] : 0.f;
    float ss = e * e;
    #pragma unroll
    for (int m = 32; m >= 1; m >>= 1) ss += __shfl_xor(ss, m, 64);
    float scale = 1.f / fmaxf(sqrtf(ss), 1.f);

    float inval = (lane < E_) ? e * scale
                : (lane < E_ + F_) ? feat[(size_t)node * F_ + (lane - E_)]
                : 0.f;

    float acc = encb[lane];
    #pragma unroll
    for (int i = 0; i < E_ + F_; ++i)
        acc = fmaf(__shfl(inval, i, 64), encW[i * D_ + lane], acc);
    h[(size_t)node * D_ + lane] = acc;
}

// ---------- per-thread row GEMM helpers: 1 row x 4 cols (A, W in LDS) -------
__device__ __forceinline__ void mmrow_g(
    const float* Arow, const float* W, int c0, float acc[4])
{
    #pragma unroll 4
    for (int i = 0; i < 64; i += 4) {
        float4 a = *(const float4*)&Arow[i];
        #pragma unroll
        for (int ii = 0; ii < 4; ++ii) {
            float av = (ii == 0) ? a.x : (ii == 1) ? a.y : (ii == 2) ? a.z : a.w;
            float4 w = *(const float4*)&W[(i + ii) * 64 + c0];
            acc[0] = fmaf(av, w.x, acc[0]);
            acc[1] = fmaf(av, w.y, acc[1]);
            acc[2] = fmaf(av, w.z, acc[2]);
            acc[3] = fmaf(av, w.w, acc[3]);
        }
    }
}

__device__ __forceinline__ void mmrow_kv(
    const float* Arow, const float* Wk, const float* Wv,
    int c0, float ak[4], float av[4])
{
    #pragma unroll 4
    for (int i = 0; i < 64; i += 4) {
        float4 a = *(const float4*)&Arow[i];
        #pragma unroll
        for (int ii = 0; ii < 4; ++ii) {
            float aa = (ii == 0) ? a.x : (ii == 1) ? a.y : (ii == 2) ? a.z : a.w;
            float4 wk = *(const float4*)&Wk[(i + ii) * 64 + c0];
            float4 wv = *(const float4*)&Wv[(i + ii) * 64 + c0];
            ak[0] = fmaf(aa, wk.x, ak[0]);
            ak[1] = fmaf(aa, wk.y, ak[1]);
            ak[2] = fmaf(aa, wk.z, ak[2]);
            ak[3] = fmaf(aa, wk.w, ak[3]);
            av[0] = fmaf(aa, wv.x, av[0]);
            av[1] = fmaf(aa, wv.y, av[1]);
            av[2] = fmaf(aa, wv.z, av[2]);
            av[3] = fmaf(aa, wv.w, av[3]);
        }
    }
}

// cooperative 16KB weight stage: global -> LDS (256 threads)
__device__ __forceinline__ void stageW(float* dst, const float* __restrict__ src, int tx)
{
    #pragma unroll
    for (int i = tx; i < 1024; i += 256)
        ((float4*)dst)[i] = ((const float4*)src)[i];
}

// ================= fully fused graph layer (round-7 structure) ==============
// 16 nodes/block, 256 threads: thread = (row = tx>>4, cols c0=4*(tx&15)).
// Weights stream through a 32KB double-slot LDS window, re-staged per phase.
__global__ __launch_bounds__(256, 4) void k_layer(
    const float* __restrict__ hin, float* __restrict__ hout,
    const int* __restrict__ neigh, const int* __restrict__ numn,
    const float* __restrict__ nbW, const float* __restrict__ Wq,
    const float* __restrict__ Wk, const float* __restrict__ Wv,
    const float* __restrict__ Wo,
    const float* __restrict__ gWz, const float* __restrict__ gUz, const float* __restrict__ gbz,
    const float* __restrict__ gWr, const float* __restrict__ gUr, const float* __restrict__ gbr,
    const float* __restrict__ gWh, const float* __restrict__ gUh, const float* __restrict__ gbh)
{
    __shared__ float wb0[64 * 64];          // 16KB W slot A
    __shared__ float wb1[64 * 64];          // 16KB W slot B
    __shared__ float sM[3][16 * RS_];       // mean->state tiles
    __shared__ float sH[16 * RS_];          // h tile
    __shared__ float sX[16 * RS_];          // ao -> x tile
    __shared__ int   sIdx[3][256];          // neighbor ids, [t][k*16+row]

    int tx = threadIdx.x;
    int row = tx >> 4, cg = tx & 15, c0 = cg * 4;
    int g = blockIdx.x * 16 + row;          // node id (grid exact: 1250*16=20000)
    int b = g / N_;
    int pad = numn[b];
    const float4* hb4 = (const float4*)(hin + (size_t)b * N_ * D_);

    // ---- phase 0: stage Wq|nbW, h rows, neighbor ids ----
    stageW(wb0, Wq, tx);
    stageW(wb1, nbW, tx);
    *(float4*)&sH[row * RS_ + c0] = *(const float4*)&hin[(size_t)g * 64 + c0];
    #pragma unroll
    for (int t = 0; t < 3; ++t)
        sIdx[t][cg * 16 + row] = neigh[((size_t)t * BN_ + g) * K_ + cg];
    __syncthreads();

    // q = h_row @ Wq
    float qv[4] = {0.f, 0.f, 0.f, 0.f};
    mmrow_g(&sH[row * RS_], wb0, c0, qv);

    // ---- gather-mean + states for all 3 neighborhoods (row-local) ----
    #pragma unroll 1
    for (int t = 0; t < 3; ++t) {
        float4 s = make_float4(0.f, 0.f, 0.f, 0.f);
        int cnt = 0;
        #pragma unroll
        for (int k = 0; k < K_; ++k) {
            int idx = sIdx[t][k * 16 + row];
            if (idx != pad) {
                float4 v = hb4[(size_t)idx * 16 + cg];
                s.x += v.x; s.y += v.y; s.z += v.z; s.w += v.w;
                cnt++;
            }
        }
        float inv = 1.f / fmaxf((float)cnt, 1.f);
        *(float4*)&sM[t][row * RS_ + c0] =
            make_float4(s.x * inv, s.y * inv, s.z * inv, s.w * inv);

        float sr[4] = {0.f, 0.f, 0.f, 0.f};
        mmrow_g(&sM[t][row * RS_], wb1, c0, sr);      // mean @ nbW
        *(float4*)&sM[t][row * RS_ + c0] =
            make_float4(tanhf(sr[0]), tanhf(sr[1]), tanhf(sr[2]), tanhf(sr[3]));
    }
    __syncthreads();

    // ---- phase 1: Wk|Wv; kk,vv + scores ----
    stageW(wb0, Wk, tx);
    stageW(wb1, Wv, tx);
    __syncthreads();

    float av[3][4];
    float p[3];
    #pragma unroll 1
    for (int t = 0; t < 3; ++t) {
        float ak[4] = {0.f, 0.f, 0.f, 0.f};
        av[t][0] = av[t][1] = av[t][2] = av[t][3] = 0.f;
        mmrow_kv(&sM[t][row * RS_], wb0, wb1, c0, ak, av[t]);
        float pp = ak[0] * qv[0] + ak[1] * qv[1] + ak[2] * qv[2] + ak[3] * qv[3];
        pp += __shfl_xor(pp, 1, 64);
        pp += __shfl_xor(pp, 2, 64);
        p[t] = pp * 0.25f;                  // / sqrt(dh=16)
    }

    // softmax over t; ao -> sX row
    float mx = fmaxf(p[0], fmaxf(p[1], p[2]));
    float e0 = expf(p[0] - mx), e1 = expf(p[1] - mx), e2 = expf(p[2] - mx);
    float winv = 1.f / (e0 + e1 + e2);
    float w0 = e0 * winv, w1 = e1 * winv, w2 = e2 * winv;
    *(float4*)&sX[row * RS_ + c0] = make_float4(
        w0 * av[0][0] + w1 * av[1][0] + w2 * av[2][0],
        w0 * av[0][1] + w1 * av[1][1] + w2 * av[2][1],
        w0 * av[0][2] + w1 * av[1][2] + w2 * av[2][2],
        w0 * av[0][3] + w1 * av[1][3] + w2 * av[2][3]);
    __syncthreads();

    // ---- phase 2: Wo|gWz; x = tanh(ao@Wo); az = x@gWz ----
    stageW(wb0, Wo, tx);
    stageW(wb1, gWz, tx);
    __syncthreads();
    float xr[4] = {0.f, 0.f, 0.f, 0.f};
    mmrow_g(&sX[row * RS_], wb0, c0, xr);             // ao @ Wo
    *(float4*)&sX[row * RS_ + c0] =
        make_float4(tanhf(xr[0]), tanhf(xr[1]), tanhf(xr[2]), tanhf(xr[3]));
    float az[4] = {0.f, 0.f, 0.f, 0.f};
    mmrow_g(&sX[row * RS_], wb1, c0, az);             // x @ gWz (own row, same wave)
    __syncthreads();

    // ---- phase 3: gUz|gWr ----
    stageW(wb0, gUz, tx);
    stageW(wb1, gWr, tx);
    __syncthreads();
    mmrow_g(&sH[row * RS_], wb0, c0, az);             // += h @ gUz
    float ar[4] = {0.f, 0.f, 0.f, 0.f};
    mmrow_g(&sX[row * RS_], wb1, c0, ar);             // x @ gWr
    __syncthreads();

    // ---- phase 4: gUr|gWh ----
    stageW(wb0, gUr, tx);
    stageW(wb1, gWh, tx);
    __syncthreads();
    mmrow_g(&sH[row * RS_], wb0, c0, ar);             // += h @ gUr

    float4 bzv = *(const float4*)&gbz[c0];
    float4 brv = *(const float4*)&gbr[c0];
    float4 hv  = *(const float4*)&sH[row * RS_ + c0];
    float z[4], rr[4];
    z[0] = 1.f / (1.f + expf(-(az[0] + bzv.x)));
    z[1] = 1.f / (1.f + expf(-(az[1] + bzv.y)));
    z[2] = 1.f / (1.f + expf(-(az[2] + bzv.z)));
    z[3] = 1.f / (1.f + expf(-(az[3] + bzv.w)));
    rr[0] = 1.f / (1.f + expf(-(ar[0] + brv.x)));
    rr[1] = 1.f / (1.f + expf(-(ar[1] + brv.y)));
    rr[2] = 1.f / (1.f + expf(-(ar[2] + brv.z)));
    rr[3] = 1.f / (1.f + expf(-(ar[3] + brv.w)));
    *(float4*)&sM[0][row * RS_ + c0] =                // rh tile (sM[0] is dead)
        make_float4(rr[0] * hv.x, rr[1] * hv.y, rr[2] * hv.z, rr[3] * hv.w);

    float ah[4] = {0.f, 0.f, 0.f, 0.f};
    mmrow_g(&sX[row * RS_], wb1, c0, ah);             // x @ gWh
    __syncthreads();

    // ---- phase 5: gUh ----
    stageW(wb0, gUh, tx);
    __syncthreads();
    mmrow_g(&sM[0][row * RS_], wb0, c0, ah);          // += rh @ gUh

    float4 bhv = *(const float4*)&gbh[c0];
    float o0 = (1.f - z[0]) * hv.x + z[0] * tanhf(ah[0] + bhv.x);
    float o1 = (1.f - z[1]) * hv.y + z[1] * tanhf(ah[1] + bhv.y);
    float o2 = (1.f - z[2]) * hv.z + z[2] * tanhf(ah[2] + bhv.z);
    float o3 = (1.f - z[3]) * hv.w + z[3] * tanhf(ah[3] + bhv.w);
    *(float4*)&hout[(size_t)g * 64 + c0] = make_float4(o0, o1, o2, o3);
}

// ---------------- edge projection ------------------------------------------
__global__ __launch_bounds__(256) void k_edgeproj(
    const float* __restrict__ h, const float* __restrict__ W1,
    float* __restrict__ P)
{
    int wave = threadIdx.x >> 6;
    int lane = threadIdx.x & 63;
    int node = blockIdx.x * 4 + wave;      // < 20000

    float hval = h[(size_t)node * D_ + lane];
    const float* wp = (lane < 32) ? (W1 + lane) : (W1 + 64 * 32 + (lane - 32));
    float acc = 0.f;
    #pragma unroll 8
    for (int i = 0; i < D_; ++i)
        acc = fmaf(__shfl(hval, i, 64), wp[i * 32], acc);
    P[(size_t)node * D_ + lane] = acc;
}

// ---------------- edge decoder (light) --------------------------------------
__global__ __launch_bounds__(256) void k_decoder2(
    const float* __restrict__ P, const int* __restrict__ adj,
    const float* __restrict__ b1, const float* __restrict__ W2,
    const float* __restrict__ b2, const int* __restrict__ num_nodes,
    float* __restrict__ nw)
{
    int half = threadIdx.x >> 5;   // 0..7
    int j    = threadIdx.x & 31;
    float bias = b1[j], w2 = W2[j], b2v = b2[0];

    #pragma unroll 1
    for (int p = 0; p < 16; ++p) {
        int e = blockIdx.x * 128 + p * 8 + half;  // edge id < 320000
        int node = e >> 4;                        // b*N+n
        int b = node / N_;
        int a = adj[e];
        int pad = num_nodes[b];
        float own = P[(size_t)node * D_ + j];
        bool pd = (a == pad);
        float nbr = pd ? 0.f : P[((size_t)b * N_ + a) * D_ + 32 + j];
        float am = pd ? 0.f : 1.f;
        float t = tanhf(bias + am * own + nbr);
        float part = t * w2;
        #pragma unroll
        for (int m = 1; m < 32; m <<= 1) part += __shfl_xor(part, m, 64);
        if (j == 0) nw[e] = part + b2v;
    }
}

// ---------------- dual vars (per node scalar) + dual_demand -----------------
__global__ __launch_bounds__(256) void k_dualvars(
    const float* __restrict__ h, const float* __restrict__ W1,
    const float* __restrict__ b1, const float* __restrict__ W2,
    const float* __restrict__ b2, const float* __restrict__ demands,
    const int* __restrict__ num_nodes,
    float* __restrict__ dv, float* __restrict__ acc_out)
{
    __shared__ float sW1[D_ * 32];
    __shared__ float sW2[32];
    __shared__ float sPart[8];
    for (int i = threadIdx.x; i < D_ * 32; i += 256) sW1[i] = W1[i];
    if (threadIdx.x < 32) sW2[threadIdx.x] = W2[threadIdx.x];
    __syncthreads();

    int half = threadIdx.x >> 5;
    int j    = threadIdx.x & 31;
    int b = (blockIdx.x * 40) / N_;
    float bias = b1[j], b2v = b2[0];
    float local = 0.f;

    #pragma unroll 1
    for (int p = 0; p < 5; ++p) {
        int node = blockIdx.x * 40 + p * 8 + half;    // < 20000
        const float* hp = h + (size_t)node * D_;
        float h0 = hp[j], h1 = hp[j + 32];
        float acc = bias;
        #pragma unroll 8
        for (int i = 0; i < 32; ++i) {
            acc = fmaf(__shfl(h0, i, 32), sW1[i * 32 + j],        acc);
            acc = fmaf(__shfl(h1, i, 32), sW1[(i + 32) * 32 + j], acc);
        }
        float t = tanhf(acc);
        float part = t * sW2[j];
        #pragma unroll
        for (int m = 1; m < 32; m <<= 1) part += __shfl_xor(part, m, 64);
        if (j == 0) {
            float v = part + b2v;
            dv[node] = v;
            local += v * demands[node];
        }
    }
    if (j == 0) sPart[half] = local;
    __syncthreads();
    if (threadIdx.x == 0) {
        float s = 0.f;
        #pragma unroll
        for (int i = 0; i < 8; ++i) s += sPart[i];
        atomicAdd(&acc_out[(b * 3 + 2) * 16], s);
    }
}

// ---------------- dest softmax over permuted groups -------------------------
__global__ void k_dest(
    const float* __restrict__ nw, const int* __restrict__ in_idx,
    const int* __restrict__ inv_adj, const int* __restrict__ num_nodes,
    float* __restrict__ dest)
{
    int t = blockIdx.x * 256 + threadIdx.x;
    if (t >= BN_) return;
    int b = t / N_;
    int pad = num_nodes[b];
    float vals[K_]; float mx = -INFINITY;
    #pragma unroll
    for (int k = 0; k < K_; ++k) {
        int jj = in_idx[(size_t)t * K_ + k];
        float g = nw[(size_t)b * NK_ + jj];
        float im = (inv_adj[(size_t)t * K_ + k] == pad) ? 1.f : 0.f;
        float v = g - BIG_ * im;
        vals[k] = v; mx = fmaxf(mx, v);
    }
    float s = 0.f;
    #pragma unroll
    for (int k = 0; k < K_; ++k) { vals[k] = expf(vals[k] - mx); s += vals[k]; }
    float invs = 1.f / s;
    #pragma unroll
    for (int k = 0; k < K_; ++k) dest[(size_t)t * K_ + k] = vals[k] * invs;
}

// ---------------- normalized_weights ----------------------------------------
__global__ void k_normw(
    const float* __restrict__ nw, const float* __restrict__ dest,
    const int* __restrict__ rev, const int* __restrict__ adj,
    const int* __restrict__ num_nodes,
    float* __restrict__ normw)
{
    int t = blockIdx.x * 256 + threadIdx.x;
    if (t >= BN_) return;
    int b = t / N_;
    int pad = num_nodes[b];
    float vals[K_]; float mx = -INFINITY;
    #pragma unroll
    for (int k = 0; k < K_; ++k) {
        size_t e = (size_t)t * K_ + k;
        float v = nw[e] * dest[(size_t)b * NK_ + rev[e]];
        float m = (adj[e] == pad) ? 1.f : 0.f;
        v -= BIG_ * m;
        vals[k] = v; mx = fmaxf(mx, v);
    }
    float s = 0.f;
    #pragma unroll
    for (int k = 0; k < K_; ++k) { vals[k] = expf(vals[k] - mx); s += vals[k]; }
    float invs = 1.f / s;
    #pragma unroll
    for (int k = 0; k < K_; ++k)
        normw[(size_t)t * K_ + k] = vals[k] * invs;
}

// ---------------- flow prep: supply, iteration weights + source nodes -------
// tot-space recurrence: tot_{i+1}[t] = supply[t] + sum_k wgt[t,k]*tot_i[srcn[t,k]]
// with wgt[t,k] = inv_valid * normw_flat[b][j], srcn[t,k] = b*N + (j>>4), j=inidx
__global__ void k_prep(
    const float* __restrict__ normw, const int* __restrict__ in_idx,
    const int* __restrict__ inv_adj, const int* __restrict__ num_nodes,
    const float* __restrict__ demands,
    float* __restrict__ supply, float* __restrict__ wgt, int* __restrict__ srcn,
    float* __restrict__ tot0)
{
    int t = blockIdx.x * 256 + threadIdx.x;
    if (t >= BN_) return;
    int b = t / N_;
    int pad = num_nodes[b];
    float sup = fmaxf(-demands[t], 0.f);
    supply[t] = sup;
    tot0[t] = sup;
    #pragma unroll
    for (int k = 0; k < K_; ++k) {
        size_t e = (size_t)t * K_ + k;
        int j = in_idx[e];
        bool valid = (inv_adj[e] != pad);
        wgt[e] = valid ? normw[(size_t)b * NK_ + j] : 0.f;
        srcn[e] = b * N_ + (j >> 4);
    }
}

// ---------------- one tot-space flow step (80KB state) ----------------------
__global__ void k_flowT(
    const float* __restrict__ totIn, const float* __restrict__ wgt,
    const int* __restrict__ srcn, const float* __restrict__ supply,
    float* __restrict__ totOut)
{
    int t = blockIdx.x * 256 + threadIdx.x;
    if (t >= BN_) return;
    float s = supply[t];
    #pragma unroll
    for (int k = 0; k < K_; ++k) {
        size_t e = (size_t)t * K_ + k;
        s = fmaf(wgt[e], totIn[srcn[e]], s);
    }
    totOut[t] = s;
}

// ---------------- dual iterations + both cost reductions --------------------
// flow[e] = normw[e] * tot10[node]
__global__ __launch_bounds__(256) void k_dualred(
    const float* __restrict__ el, const float* __restrict__ dv,
    const int* __restrict__ adj, const int* __restrict__ num_nodes,
    const float* __restrict__ normw, const float* __restrict__ tot10,
    float* __restrict__ acc_out)
{
    int b = blockIdx.y;
    int ein = blockIdx.x * 256 + threadIdx.x;
    float c0 = 0.f, c1 = 0.f;
    if (ein < NK_) {
        size_t e = (size_t)b * NK_ + ein;
        int pad = num_nodes[b];
        int node = b * N_ + (ein >> 4);
        int a = adj[e];
        float am = (a == pad) ? 0.f : 1.f;
        float dtr = (a == pad) ? 0.f : dv[(size_t)b * N_ + a];
        float d = dtr - am * dv[node];
        float l = el[e];
        float f = 0.f, ac = 0.f;
        #pragma unroll
        for (int it = 0; it < 10; ++it) {
            float g = 2.f * l * f + d;
            ac = 0.9f * ac + 0.01f * g;
            f = fmaxf(f - ac, 0.f) * am;
        }
        float fl = normw[e] * tot10[node];
        c0 = l * fl * fl;          // flow_cost term
        c1 = l * f * f + d * f;    // dual flow term
    }
    #pragma unroll
    for (int m = 1; m < 64; m <<= 1) { c0 += __shfl_xor(c0, m, 64); c1 += __shfl_xor(c1, m, 64); }
    __shared__ float s0[4], s1[4];
    int wave = threadIdx.x >> 6, lane = threadIdx.x & 63;
    if (lane == 0) { s0[wave] = c0; s1[wave] = c1; }
    __syncthreads();
    if (threadIdx.x == 0) {
        atomicAdd(&acc_out[(b * 3 + 0) * 16], s0[0] + s0[1] + s0[2] + s0[3]);
        atomicAdd(&acc_out[(b * 3 + 1) * 16], s1[0] + s1[1] + s1[2] + s1[3]);
    }
}

// ---------------- finalize --------------------------------------------------
__global__ void k_final(const float* __restrict__ acc, float* __restrict__ out) {
    int b = threadIdx.x;
    if (b < B_)
        out[b] = acc[(b * 3 + 0) * 16] - acc[(b * 3 + 1) * 16] + acc[(b * 3 + 2) * 16];
}

extern "C" void kernel_launch(void* const* d_in, const int* in_sizes, int n_in,
                              void* d_out, int out_size, void* d_ws, size_t ws_size,
                              hipStream_t stream)
{
    const float* demands = (const float*)d_in[0];
    const float* feat    = (const float*)d_in[1];
    const float* el      = (const float*)d_in[2];
    const float* embed   = (const float*)d_in[3];
    const float* encW    = (const float*)d_in[4];
    const float* encb    = (const float*)d_in[5];
    const float* nbW     = (const float*)d_in[6];
    const float* Wq      = (const float*)d_in[7];
    const float* Wk      = (const float*)d_in[8];
    const float* Wv      = (const float*)d_in[9];
    const float* Wo      = (const float*)d_in[10];
    const float* gWz     = (const float*)d_in[11];
    const float* gUz     = (const float*)d_in[12];
    const float* gbz     = (const float*)d_in[13];
    const float* gWr     = (const float*)d_in[14];
    const float* gUr     = (const float*)d_in[15];
    const float* gbr     = (const float*)d_in[16];
    const float* gWh     = (const float*)d_in[17];
    const float* gUh     = (const float*)d_in[18];
    const float* gbh     = (const float*)d_in[19];
    const float* decW1   = (const float*)d_in[20];
    const float* decb1   = (const float*)d_in[21];
    const float* decW2   = (const float*)d_in[22];
    const float* decb2   = (const float*)d_in[23];
    const float* dualW1  = (const float*)d_in[24];
    const float* dualb1  = (const float*)d_in[25];
    const float* dualW2  = (const float*)d_in[26];
    const float* dualb2  = (const float*)d_in[27];
    const int* adj       = (const int*)d_in[28];
    const int* invadj    = (const int*)d_in[29];
    const int* neigh     = (const int*)d_in[30];
    const int* inidx     = (const int*)d_in[31];
    const int* revidx    = (const int*)d_in[32];
    const int* numn      = (const int*)d_in[33];

    // workspace (floats), ~17MB
    float* ws     = (float*)d_ws;
    float* h0     = ws;                   // 1,280,000
    float* h1     = ws + 1280000;         // 1,280,000 (ping-pong; P after layers)
    float* nw     = ws + 2560000;         // 320,000
    float* dest   = ws + 2880000;         // 320,000
    float* normw  = ws + 3200000;         // 320,000
    float* wgt    = ws + 3520000;         // 320,000
    int*   srcn   = (int*)(ws + 3840000); // 320,000 ints
    float* totA   = ws + 4160000;         // 20,000
    float* totB   = ws + 4180000;         // 20,000
    float* supply = ws + 4200000;         // 20,000
    float* dv     = ws + 4220000;         // 20,000
    float* P      = h1;                   // reuse (h1 dead after layer 1)
    float* acc    = ws + 4240000;         // 192

    k_zero<<<1, 256, 0, stream>>>(acc);
    k_encode<<<BN_ / 4, 256, 0, stream>>>(embed, feat, encW, encb, h0);

    // layer 0: h0 -> h1 ; layer 1: h1 -> h0  (gathers must read pre-layer h)
    k_layer<<<BN_ / 16, 256, 0, stream>>>(h0, h1, neigh, numn, nbW, Wq, Wk, Wv, Wo,
                                          gWz, gUz, gbz, gWr, gUr, gbr, gWh, gUh, gbh);
    k_layer<<<BN_ / 16, 256, 0, stream>>>(h1, h0, neigh, numn, nbW, Wq, Wk, Wv, Wo,
                                          gWz, gUz, gbz, gWr, gUr, gbr, gWh, gUh, gbh);
    float* h = h0;

    k_edgeproj<<<BN_ / 4, 256, 0, stream>>>(h, decW1, P);
    k_decoder2<<<(B_ * NK_) / 128, 256, 0, stream>>>(P, adj, decb1, decW2, decb2, numn, nw);
    k_dualvars<<<BN_ / 40, 256, 0, stream>>>(h, dualW1, dualb1, dualW2, dualb2, demands, numn, dv, acc);
    k_dest<<<(BN_ + 255) / 256, 256, 0, stream>>>(nw, inidx, invadj, numn, dest);
    k_normw<<<(BN_ + 255) / 256, 256, 0, stream>>>(nw, dest, revidx, adj, numn, normw);
    k_prep<<<(BN_ + 255) / 256, 256, 0, stream>>>(normw, inidx, invadj, numn, demands,
                                                  supply, wgt, srcn, totA);

    float* cur = totA; float* nxt = totB;
    for (int it = 0; it < 10; ++it) {
        k_flowT<<<(BN_ + 255) / 256, 256, 0, stream>>>(cur, wgt, srcn, supply, nxt);
        float* tmp = cur; cur = nxt; nxt = tmp;
    }

    dim3 gred((NK_ + 255) / 256, B_);
    k_dualred<<<gred, 256, 0, stream>>>(el, dv, adj, numn, normw, cur, acc);
    k_final<<<1, 64, 0, stream>>>(acc, (float*)d_out);
}

// Round 10
// 369.078 us; speedup vs baseline: 1.9086x; 1.1686x over previous
//
#include <hip/hip_runtime.h>
#include <math.h>

#define B_ 4
#define N_ 5000
#define K_ 16
#define L_ 3
#define F_ 2
#define E_ 32
#define D_ 64
#define H_ 4
#define BN_ (B_*N_)          /* 20000 */
#define NK_ (N_*K_)          /* 80000 */
#define BIG_ 1.0e9f
#define RS_ 68               /* padded LDS row stride (floats) */

// ---------------- zero the accumulators -------------------------------------
__global__ void k_zero(float* __restrict__ acc) {
    if (threadIdx.x < 192) acc[threadIdx.x] = 0.f;
}

// ---------------- encoder: h = [emb_norm, feat] @ enc_W + enc_b -------------
__global__ __launch_bounds__(256) void k_encode(
    const float* __restrict__ embed, const float* __restrict__ feat,
    const float* __restrict__ encW, const float* __restrict__ encb,
    float* __restrict__ h)
{
    int wave = threadIdx.x >> 6;
    int lane = threadIdx.x & 63;
    int node = blockIdx.x * 4 + wave;      // b*N+n  in [0,20000)
    int n = node % N_;

    float e = (lane < E_) ? embed[(size_t)n * E_ + lane] : 0.f;
    float ss = e * e;
    #pragma unroll
    for (int m = 32; m >= 1; m >>= 1) ss += __shfl_xor(ss, m, 64);
    float scale = 1.f / fmaxf(sqrtf(ss), 1.f);

    float inval = (lane < E_) ? e * scale
                : (lane < E_ + F_) ? feat[(size_t)node * F_ + (lane - E_)]
                : 0.f;

    float acc = encb[lane];
    #pragma unroll
    for (int i = 0; i < E_ + F_; ++i)
        acc = fmaf(__shfl(inval, i, 64), encW[i * D_ + lane], acc);
    h[(size_t)node * D_ + lane] = acc;
}

// ---------- per-thread row GEMM helpers: 1 row x 4 cols (A, W in LDS) -------
__device__ __forceinline__ void mmrow_g(
    const float* Arow, const float* W, int c0, float acc[4])
{
    #pragma unroll 4
    for (int i = 0; i < 64; i += 4) {
        float4 a = *(const float4*)&Arow[i];
        #pragma unroll
        for (int ii = 0; ii < 4; ++ii) {
            float av = (ii == 0) ? a.x : (ii == 1) ? a.y : (ii == 2) ? a.z : a.w;
            float4 w = *(const float4*)&W[(i + ii) * 64 + c0];
            acc[0] = fmaf(av, w.x, acc[0]);
            acc[1] = fmaf(av, w.y, acc[1]);
            acc[2] = fmaf(av, w.z, acc[2]);
            acc[3] = fmaf(av, w.w, acc[3]);
        }
    }
}

// combined 3-source A row (w0*A0 + w1*A1 + w2*A2) @ W
__device__ __forceinline__ void mmrow_3c(
    const float* A0, const float* A1, const float* A2,
    float w0, float w1, float w2,
    const float* W, int c0, float acc[4])
{
    #pragma unroll 4
    for (int i = 0; i < 64; i += 4) {
        float4 a0 = *(const float4*)&A0[i];
        float4 a1 = *(const float4*)&A1[i];
        float4 a2 = *(const float4*)&A2[i];
        float ac[4];
        ac[0] = fmaf(w0, a0.x, fmaf(w1, a1.x, w2 * a2.x));
        ac[1] = fmaf(w0, a0.y, fmaf(w1, a1.y, w2 * a2.y));
        ac[2] = fmaf(w0, a0.z, fmaf(w1, a1.z, w2 * a2.z));
        ac[3] = fmaf(w0, a0.w, fmaf(w1, a1.w, w2 * a2.w));
        #pragma unroll
        for (int ii = 0; ii < 4; ++ii) {
            float4 w = *(const float4*)&W[(i + ii) * 64 + c0];
            acc[0] = fmaf(ac[ii], w.x, acc[0]);
            acc[1] = fmaf(ac[ii], w.y, acc[1]);
            acc[2] = fmaf(ac[ii], w.z, acc[2]);
            acc[3] = fmaf(ac[ii], w.w, acc[3]);
        }
    }
}

// cooperative 16KB weight stage: global -> LDS (256 threads), stride 64
__device__ __forceinline__ void stageW(float* dst, const float* __restrict__ src, int tx)
{
    #pragma unroll
    for (int i = tx; i < 1024; i += 256)
        ((float4*)dst)[i] = ((const float4*)src)[i];
}

// transposed stage at stride RS_ (for the y-pass): dst[c'*RS_ + c] = src[c*64+c']
__device__ __forceinline__ void stageWT(float* dst, const float* __restrict__ src, int tx)
{
    #pragma unroll
    for (int i = tx; i < 4096; i += 256)
        dst[(i & 63) * RS_ + (i >> 6)] = src[i];
}

// ================= fully fused graph layer (13-pass schedule) ===============
// 16 nodes/block, 256 threads: thread = (row = tx>>4, cols c0=4*(tx&15)).
// Weights stream through a double-slot LDS window, re-staged per phase.
// Passes: q(1) states(3) y(1) ao(1) x(1) z(2) r(2) h(2) = 13 (was 17).
__global__ __launch_bounds__(256, 4) void k_layer(
    const float* __restrict__ hin, float* __restrict__ hout,
    const int* __restrict__ neigh, const int* __restrict__ numn,
    const float* __restrict__ nbW, const float* __restrict__ Wq,
    const float* __restrict__ Wk, const float* __restrict__ Wv,
    const float* __restrict__ Wo,
    const float* __restrict__ gWz, const float* __restrict__ gUz, const float* __restrict__ gbz,
    const float* __restrict__ gWr, const float* __restrict__ gUr, const float* __restrict__ gbr,
    const float* __restrict__ gWh, const float* __restrict__ gUh, const float* __restrict__ gbh)
{
    __shared__ float wb0[64 * RS_];         // W slot A (17KB; stride 64 normally, RS_ for Wk^T)
    __shared__ float wb1[64 * 64];          // W slot B (16KB)
    __shared__ float sM[3][16 * RS_];       // mean->state tiles
    __shared__ float sH[16 * RS_];          // h tile
    __shared__ float sX[16 * RS_];          // q -> ao -> x tile
    __shared__ int   sIdx[3][256];          // neighbor ids, [t][k*16+row]

    int tx = threadIdx.x;
    int row = tx >> 4, cg = tx & 15, c0 = cg * 4;
    int g = blockIdx.x * 16 + row;          // node id (grid exact: 1250*16=20000)
    int b = g / N_;
    int pad = numn[b];
    const float4* hb4 = (const float4*)(hin + (size_t)b * N_ * D_);

    // ---- phase 0: stage Wq|nbW, h rows, neighbor ids ----
    stageW(wb0, Wq, tx);
    stageW(wb1, nbW, tx);
    *(float4*)&sH[row * RS_ + c0] = *(const float4*)&hin[(size_t)g * 64 + c0];
    #pragma unroll
    for (int t = 0; t < 3; ++t)
        sIdx[t][cg * 16 + row] = neigh[((size_t)t * BN_ + g) * K_ + cg];
    __syncthreads();

    // q = h_row @ Wq -> sX row (needed in full by the y-pass)
    {
        float qv[4] = {0.f, 0.f, 0.f, 0.f};
        mmrow_g(&sH[row * RS_], wb0, c0, qv);
        *(float4*)&sX[row * RS_ + c0] = make_float4(qv[0], qv[1], qv[2], qv[3]);
    }

    // ---- gather-mean + states for all 3 neighborhoods (row-local) ----
    #pragma unroll 1
    for (int t = 0; t < 3; ++t) {
        float4 s = make_float4(0.f, 0.f, 0.f, 0.f);
        int cnt = 0;
        #pragma unroll
        for (int k = 0; k < K_; ++k) {
            int idx = sIdx[t][k * 16 + row];
            if (idx != pad) {
                float4 v = hb4[(size_t)idx * 16 + cg];
                s.x += v.x; s.y += v.y; s.z += v.z; s.w += v.w;
                cnt++;
            }
        }
        float inv = 1.f / fmaxf((float)cnt, 1.f);
        *(float4*)&sM[t][row * RS_ + c0] =
            make_float4(s.x * inv, s.y * inv, s.z * inv, s.w * inv);

        float sr[4] = {0.f, 0.f, 0.f, 0.f};
        mmrow_g(&sM[t][row * RS_], wb1, c0, sr);      // mean @ nbW
        *(float4*)&sM[t][row * RS_ + c0] =
            make_float4(tanhf(sr[0]), tanhf(sr[1]), tanhf(sr[2]), tanhf(sr[3]));
    }
    __syncthreads();

    // ---- phase 1: Wk^T (stride RS_) | Wv ----
    stageWT(wb0, Wk, tx);
    stageW(wb1, Wv, tx);
    __syncthreads();

    // y-pass: y[h][r] = sum_{c' in head h} Wk[c0+r][c'] * q[c']
    float y[4][4] = {};
    #pragma unroll
    for (int i = 0; i < 64; i += 4) {
        float4 q4 = *(const float4*)&sX[row * RS_ + i];
        const int h = i >> 4;                         // compile-time under unroll
        #pragma unroll
        for (int ii = 0; ii < 4; ++ii) {
            float qe = (ii == 0) ? q4.x : (ii == 1) ? q4.y : (ii == 2) ? q4.z : q4.w;
            float4 w = *(const float4*)&wb0[(i + ii) * RS_ + c0];
            y[h][0] = fmaf(qe, w.x, y[h][0]);
            y[h][1] = fmaf(qe, w.y, y[h][1]);
            y[h][2] = fmaf(qe, w.z, y[h][2]);
            y[h][3] = fmaf(qe, w.w, y[h][3]);
        }
    }

    // scores p[t][h] = s_t . y_h (reduce over the 16-lane row group), softmax
    float w0, w1, w2;
    {
        float pt[3][4];
        #pragma unroll
        for (int t = 0; t < 3; ++t) {
            float4 st = *(const float4*)&sM[t][row * RS_ + c0];
            #pragma unroll
            for (int h = 0; h < 4; ++h) {
                float pp = st.x * y[h][0] + st.y * y[h][1]
                         + st.z * y[h][2] + st.w * y[h][3];
                pp += __shfl_xor(pp, 1, 64);
                pp += __shfl_xor(pp, 2, 64);
                pp += __shfl_xor(pp, 4, 64);
                pp += __shfl_xor(pp, 8, 64);
                pt[t][h] = pp * 0.25f;                // / sqrt(dh=16)
            }
        }
        int ho = cg >> 2;                             // head of this thread's cols
        float p0 = (ho == 0) ? pt[0][0] : (ho == 1) ? pt[0][1] : (ho == 2) ? pt[0][2] : pt[0][3];
        float p1 = (ho == 0) ? pt[1][0] : (ho == 1) ? pt[1][1] : (ho == 2) ? pt[1][2] : pt[1][3];
        float p2 = (ho == 0) ? pt[2][0] : (ho == 1) ? pt[2][1] : (ho == 2) ? pt[2][2] : pt[2][3];
        float mx = fmaxf(p0, fmaxf(p1, p2));
        float e0 = expf(p0 - mx), e1 = expf(p1 - mx), e2 = expf(p2 - mx);
        float inv = 1.f / (e0 + e1 + e2);
        w0 = e0 * inv; w1 = e1 * inv; w2 = e2 * inv;
    }

    // ao = (w0*s0 + w1*s1 + w2*s2) @ Wv  -> sX (q is dead)
    {
        float ao[4] = {0.f, 0.f, 0.f, 0.f};
        mmrow_3c(&sM[0][row * RS_], &sM[1][row * RS_], &sM[2][row * RS_],
                 w0, w1, w2, wb1, c0, ao);
        *(float4*)&sX[row * RS_ + c0] = make_float4(ao[0], ao[1], ao[2], ao[3]);
    }
    __syncthreads();

    // ---- phase 2: Wo|gWz; x = tanh(ao@Wo); az = x@gWz ----
    stageW(wb0, Wo, tx);
    stageW(wb1, gWz, tx);
    __syncthreads();
    float xr[4] = {0.f, 0.f, 0.f, 0.f};
    mmrow_g(&sX[row * RS_], wb0, c0, xr);             // ao @ Wo
    *(float4*)&sX[row * RS_ + c0] =
        make_float4(tanhf(xr[0]), tanhf(xr[1]), tanhf(xr[2]), tanhf(xr[3]));
    float az[4] = {0.f, 0.f, 0.f, 0.f};
    mmrow_g(&sX[row * RS_], wb1, c0, az);             // x @ gWz (own row, same wave)
    __syncthreads();

    // ---- phase 3: gUz|gWr ----
    stageW(wb0, gUz, tx);
    stageW(wb1, gWr, tx);
    __syncthreads();
    mmrow_g(&sH[row * RS_], wb0, c0, az);             // += h @ gUz
    float ar[4] = {0.f, 0.f, 0.f, 0.f};
    mmrow_g(&sX[row * RS_], wb1, c0, ar);             // x @ gWr
    __syncthreads();

    // ---- phase 4: gUr|gWh ----
    stageW(wb0, gUr, tx);
    stageW(wb1, gWh, tx);
    __syncthreads();
    mmrow_g(&sH[row * RS_], wb0, c0, ar);             // += h @ gUr

    float4 bzv = *(const float4*)&gbz[c0];
    float4 brv = *(const float4*)&gbr[c0];
    float4 hv  = *(const float4*)&sH[row * RS_ + c0];
    float z[4], rr[4];
    z[0] = 1.f / (1.f + expf(-(az[0] + bzv.x)));
    z[1] = 1.f / (1.f + expf(-(az[1] + bzv.y)));
    z[2] = 1.f / (1.f + expf(-(az[2] + bzv.z)));
    z[3] = 1.f / (1.f + expf(-(az[3] + bzv.w)));
    rr[0] = 1.f / (1.f + expf(-(ar[0] + brv.x)));
    rr[1] = 1.f / (1.f + expf(-(ar[1] + brv.y)));
    rr[2] = 1.f / (1.f + expf(-(ar[2] + brv.z)));
    rr[3] = 1.f / (1.f + expf(-(ar[3] + brv.w)));
    *(float4*)&sM[0][row * RS_ + c0] =                // rh tile (sM[0] is dead)
        make_float4(rr[0] * hv.x, rr[1] * hv.y, rr[2] * hv.z, rr[3] * hv.w);

    float ah[4] = {0.f, 0.f, 0.f, 0.f};
    mmrow_g(&sX[row * RS_], wb1, c0, ah);             // x @ gWh
    __syncthreads();

    // ---- phase 5: gUh ----
    stageW(wb0, gUh, tx);
    __syncthreads();
    mmrow_g(&sM[0][row * RS_], wb0, c0, ah);          // += rh @ gUh

    float4 bhv = *(const float4*)&gbh[c0];
    float o0 = (1.f - z[0]) * hv.x + z[0] * tanhf(ah[0] + bhv.x);
    float o1 = (1.f - z[1]) * hv.y + z[1] * tanhf(ah[1] + bhv.y);
    float o2 = (1.f - z[2]) * hv.z + z[2] * tanhf(ah[2] + bhv.z);
    float o3 = (1.f - z[3]) * hv.w + z[3] * tanhf(ah[3] + bhv.w);
    *(float4*)&hout[(size_t)g * 64 + c0] = make_float4(o0, o1, o2, o3);
}

// ---------------- edge projection ------------------------------------------
__global__ __launch_bounds__(256) void k_edgeproj(
    const float* __restrict__ h, const float* __restrict__ W1,
    float* __restrict__ P)
{
    int wave = threadIdx.x >> 6;
    int lane = threadIdx.x & 63;
    int node = blockIdx.x * 4 + wave;      // < 20000

    float hval = h[(size_t)node * D_ + lane];
    const float* wp = (lane < 32) ? (W1 + lane) : (W1 + 64 * 32 + (lane - 32));
    float acc = 0.f;
    #pragma unroll 8
    for (int i = 0; i < D_; ++i)
        acc = fmaf(__shfl(hval, i, 64), wp[i * 32], acc);
    P[(size_t)node * D_ + lane] = acc;
}

// ---------------- edge decoder (light) --------------------------------------
__global__ __launch_bounds__(256) void k_decoder2(
    const float* __restrict__ P, const int* __restrict__ adj,
    const float* __restrict__ b1, const float* __restrict__ W2,
    const float* __restrict__ b2, const int* __restrict__ num_nodes,
    float* __restrict__ nw)
{
    int half = threadIdx.x >> 5;   // 0..7
    int j    = threadIdx.x & 31;
    float bias = b1[j], w2 = W2[j], b2v = b2[0];

    #pragma unroll 1
    for (int p = 0; p < 16; ++p) {
        int e = blockIdx.x * 128 + p * 8 + half;  // edge id < 320000
        int node = e >> 4;                        // b*N+n
        int b = node / N_;
        int a = adj[e];
        int pad = num_nodes[b];
        float own = P[(size_t)node * D_ + j];
        bool pd = (a == pad);
        float nbr = pd ? 0.f : P[((size_t)b * N_ + a) * D_ + 32 + j];
        float am = pd ? 0.f : 1.f;
        float t = tanhf(bias + am * own + nbr);
        float part = t * w2;
        #pragma unroll
        for (int m = 1; m < 32; m <<= 1) part += __shfl_xor(part, m, 64);
        if (j == 0) nw[e] = part + b2v;
    }
}

// ---------------- dual vars (per node scalar) + dual_demand -----------------
__global__ __launch_bounds__(256) void k_dualvars(
    const float* __restrict__ h, const float* __restrict__ W1,
    const float* __restrict__ b1, const float* __restrict__ W2,
    const float* __restrict__ b2, const float* __restrict__ demands,
    const int* __restrict__ num_nodes,
    float* __restrict__ dv, float* __restrict__ acc_out)
{
    __shared__ float sW1[D_ * 32];
    __shared__ float sW2[32];
    __shared__ float sPart[8];
    for (int i = threadIdx.x; i < D_ * 32; i += 256) sW1[i] = W1[i];
    if (threadIdx.x < 32) sW2[threadIdx.x] = W2[threadIdx.x];
    __syncthreads();

    int half = threadIdx.x >> 5;
    int j    = threadIdx.x & 31;
    int b = (blockIdx.x * 40) / N_;
    float bias = b1[j], b2v = b2[0];
    float local = 0.f;

    #pragma unroll 1
    for (int p = 0; p < 5; ++p) {
        int node = blockIdx.x * 40 + p * 8 + half;    // < 20000
        const float* hp = h + (size_t)node * D_;
        float h0 = hp[j], h1 = hp[j + 32];
        float acc = bias;
        #pragma unroll 8
        for (int i = 0; i < 32; ++i) {
            acc = fmaf(__shfl(h0, i, 32), sW1[i * 32 + j],        acc);
            acc = fmaf(__shfl(h1, i, 32), sW1[(i + 32) * 32 + j], acc);
        }
        float t = tanhf(acc);
        float part = t * sW2[j];
        #pragma unroll
        for (int m = 1; m < 32; m <<= 1) part += __shfl_xor(part, m, 64);
        if (j == 0) {
            float v = part + b2v;
            dv[node] = v;
            local += v * demands[node];
        }
    }
    if (j == 0) sPart[half] = local;
    __syncthreads();
    if (threadIdx.x == 0) {
        float s = 0.f;
        #pragma unroll
        for (int i = 0; i < 8; ++i) s += sPart[i];
        atomicAdd(&acc_out[(b * 3 + 2) * 16], s);
    }
}

// ---------------- dest softmax over permuted groups -------------------------
__global__ void k_dest(
    const float* __restrict__ nw, const int* __restrict__ in_idx,
    const int* __restrict__ inv_adj, const int* __restrict__ num_nodes,
    float* __restrict__ dest)
{
    int t = blockIdx.x * 256 + threadIdx.x;
    if (t >= BN_) return;
    int b = t / N_;
    int pad = num_nodes[b];
    float vals[K_]; float mx = -INFINITY;
    #pragma unroll
    for (int k = 0; k < K_; ++k) {
        int jj = in_idx[(size_t)t * K_ + k];
        float g = nw[(size_t)b * NK_ + jj];
        float im = (inv_adj[(size_t)t * K_ + k] == pad) ? 1.f : 0.f;
        float v = g - BIG_ * im;
        vals[k] = v; mx = fmaxf(mx, v);
    }
    float s = 0.f;
    #pragma unroll
    for (int k = 0; k < K_; ++k) { vals[k] = expf(vals[k] - mx); s += vals[k]; }
    float invs = 1.f / s;
    #pragma unroll
    for (int k = 0; k < K_; ++k) dest[(size_t)t * K_ + k] = vals[k] * invs;
}

// ---------------- normalized_weights ----------------------------------------
__global__ void k_normw(
    const float* __restrict__ nw, const float* __restrict__ dest,
    const int* __restrict__ rev, const int* __restrict__ adj,
    const int* __restrict__ num_nodes,
    float* __restrict__ normw)
{
    int t = blockIdx.x * 256 + threadIdx.x;
    if (t >= BN_) return;
    int b = t / N_;
    int pad = num_nodes[b];
    float vals[K_]; float mx = -INFINITY;
    #pragma unroll
    for (int k = 0; k < K_; ++k) {
        size_t e = (size_t)t * K_ + k;
        float v = nw[e] * dest[(size_t)b * NK_ + rev[e]];
        float m = (adj[e] == pad) ? 1.f : 0.f;
        v -= BIG_ * m;
        vals[k] = v; mx = fmaxf(mx, v);
    }
    float s = 0.f;
    #pragma unroll
    for (int k = 0; k < K_; ++k) { vals[k] = expf(vals[k] - mx); s += vals[k]; }
    float invs = 1.f / s;
    #pragma unroll
    for (int k = 0; k < K_; ++k)
        normw[(size_t)t * K_ + k] = vals[k] * invs;
}

// ---------------- flow prep: supply, iteration weights + source nodes -------
__global__ void k_prep(
    const float* __restrict__ normw, const int* __restrict__ in_idx,
    const int* __restrict__ inv_adj, const int* __restrict__ num_nodes,
    const float* __restrict__ demands,
    float* __restrict__ supply, float* __restrict__ wgt, int* __restrict__ srcn,
    float* __restrict__ tot0)
{
    int t = blockIdx.x * 256 + threadIdx.x;
    if (t >= BN_) return;
    int b = t / N_;
    int pad = num_nodes[b];
    float sup = fmaxf(-demands[t], 0.f);
    supply[t] = sup;
    tot0[t] = sup;
    #pragma unroll
    for (int k = 0; k < K_; ++k) {
        size_t e = (size_t)t * K_ + k;
        int j = in_idx[e];
        bool valid = (inv_adj[e] != pad);
        wgt[e] = valid ? normw[(size_t)b * NK_ + j] : 0.f;
        srcn[e] = b * N_ + (j >> 4);
    }
}

// ---------------- one tot-space flow step (80KB state) ----------------------
__global__ void k_flowT(
    const float* __restrict__ totIn, const float* __restrict__ wgt,
    const int* __restrict__ srcn, const float* __restrict__ supply,
    float* __restrict__ totOut)
{
    int t = blockIdx.x * 256 + threadIdx.x;
    if (t >= BN_) return;
    float s = supply[t];
    #pragma unroll
    for (int k = 0; k < K_; ++k) {
        size_t e = (size_t)t * K_ + k;
        s = fmaf(wgt[e], totIn[srcn[e]], s);
    }
    totOut[t] = s;
}

// ---------------- dual iterations + both cost reductions --------------------
__global__ __launch_bounds__(256) void k_dualred(
    const float* __restrict__ el, const float* __restrict__ dv,
    const int* __restrict__ adj, const int* __restrict__ num_nodes,
    const float* __restrict__ normw, const float* __restrict__ tot10,
    float* __restrict__ acc_out)
{
    int b = blockIdx.y;
    int ein = blockIdx.x * 256 + threadIdx.x;
    float c0 = 0.f, c1 = 0.f;
    if (ein < NK_) {
        size_t e = (size_t)b * NK_ + ein;
        int pad = num_nodes[b];
        int node = b * N_ + (ein >> 4);
        int a = adj[e];
        float am = (a == pad) ? 0.f : 1.f;
        float dtr = (a == pad) ? 0.f : dv[(size_t)b * N_ + a];
        float d = dtr - am * dv[node];
        float l = el[e];
        float f = 0.f, ac = 0.f;
        #pragma unroll
        for (int it = 0; it < 10; ++it) {
            float g = 2.f * l * f + d;
            ac = 0.9f * ac + 0.01f * g;
            f = fmaxf(f - ac, 0.f) * am;
        }
        float fl = normw[e] * tot10[node];
        c0 = l * fl * fl;          // flow_cost term
        c1 = l * f * f + d * f;    // dual flow term
    }
    #pragma unroll
    for (int m = 1; m < 64; m <<= 1) { c0 += __shfl_xor(c0, m, 64); c1 += __shfl_xor(c1, m, 64); }
    __shared__ float s0[4], s1[4];
    int wave = threadIdx.x >> 6, lane = threadIdx.x & 63;
    if (lane == 0) { s0[wave] = c0; s1[wave] = c1; }
    __syncthreads();
    if (threadIdx.x == 0) {
        atomicAdd(&acc_out[(b * 3 + 0) * 16], s0[0] + s0[1] + s0[2] + s0[3]);
        atomicAdd(&acc_out[(b * 3 + 1) * 16], s1[0] + s1[1] + s1[2] + s1[3]);
    }
}

// ---------------- finalize --------------------------------------------------
__global__ void k_final(const float* __restrict__ acc, float* __restrict__ out) {
    int b = threadIdx.x;
    if (b < B_)
        out[b] = acc[(b * 3 + 0) * 16] - acc[(b * 3 + 1) * 16] + acc[(b * 3 + 2) * 16];
}

extern "C" void kernel_launch(void* const* d_in, const int* in_sizes, int n_in,
                              void* d_out, int out_size, void* d_ws, size_t ws_size,
                              hipStream_t stream)
{
    const float* demands = (const float*)d_in[0];
    const float* feat    = (const float*)d_in[1];
    const float* el      = (const float*)d_in[2];
    const float* embed   = (const float*)d_in[3];
    const float* encW    = (const float*)d_in[4];
    const float* encb    = (const float*)d_in[5];
    const float* nbW     = (const float*)d_in[6];
    const float* Wq      = (const float*)d_in[7];
    const float* Wk      = (const float*)d_in[8];
    const float* Wv      = (const float*)d_in[9];
    const float* Wo      = (const float*)d_in[10];
    const float* gWz     = (const float*)d_in[11];
    const float* gUz     = (const float*)d_in[12];
    const float* gbz     = (const float*)d_in[13];
    const float* gWr     = (const float*)d_in[14];
    const float* gUr     = (const float*)d_in[15];
    const float* gbr     = (const float*)d_in[16];
    const float* gWh     = (const float*)d_in[17];
    const float* gUh     = (const float*)d_in[18];
    const float* gbh     = (const float*)d_in[19];
    const float* decW1   = (const float*)d_in[20];
    const float* decb1   = (const float*)d_in[21];
    const float* decW2   = (const float*)d_in[22];
    const float* decb2   = (const float*)d_in[23];
    const float* dualW1  = (const float*)d_in[24];
    const float* dualb1  = (const float*)d_in[25];
    const float* dualW2  = (const float*)d_in[26];
    const float* dualb2  = (const float*)d_in[27];
    const int* adj       = (const int*)d_in[28];
    const int* invadj    = (const int*)d_in[29];
    const int* neigh     = (const int*)d_in[30];
    const int* inidx     = (const int*)d_in[31];
    const int* revidx    = (const int*)d_in[32];
    const int* numn      = (const int*)d_in[33];

    // workspace (floats), ~17MB
    float* ws     = (float*)d_ws;
    float* h0     = ws;                   // 1,280,000
    float* h1     = ws + 1280000;         // 1,280,000 (ping-pong; P after layers)
    float* nw     = ws + 2560000;         // 320,000
    float* dest   = ws + 2880000;         // 320,000
    float* normw  = ws + 3200000;         // 320,000
    float* wgt    = ws + 3520000;         // 320,000
    int*   srcn   = (int*)(ws + 3840000); // 320,000 ints
    float* totA   = ws + 4160000;         // 20,000
    float* totB   = ws + 4180000;         // 20,000
    float* supply = ws + 4200000;         // 20,000
    float* dv     = ws + 4220000;         // 20,000
    float* P      = h1;                   // reuse (h1 dead after layer 1)
    float* acc    = ws + 4240000;         // 192

    k_zero<<<1, 256, 0, stream>>>(acc);
    k_encode<<<BN_ / 4, 256, 0, stream>>>(embed, feat, encW, encb, h0);

    // layer 0: h0 -> h1 ; layer 1: h1 -> h0  (gathers must read pre-layer h)
    k_layer<<<BN_ / 16, 256, 0, stream>>>(h0, h1, neigh, numn, nbW, Wq, Wk, Wv, Wo,
                                          gWz, gUz, gbz, gWr, gUr, gbr, gWh, gUh, gbh);
    k_layer<<<BN_ / 16, 256, 0, stream>>>(h1, h0, neigh, numn, nbW, Wq, Wk, Wv, Wo,
                                          gWz, gUz, gbz, gWr, gUr, gbr, gWh, gUh, gbh);
    float* h = h0;

    k_edgeproj<<<BN_ / 4, 256, 0, stream>>>(h, decW1, P);
    k_decoder2<<<(B_ * NK_) / 128, 256, 0, stream>>>(P, adj, decb1, decW2, decb2, numn, nw);
    k_dualvars<<<BN_ / 40, 256, 0, stream>>>(h, dualW1, dualb1, dualW2, dualb2, demands, numn, dv, acc);
    k_dest<<<(BN_ + 255) / 256, 256, 0, stream>>>(nw, inidx, invadj, numn, dest);
    k_normw<<<(BN_ + 255) / 256, 256, 0, stream>>>(nw, dest, revidx, adj, numn, normw);
    k_prep<<<(BN_ + 255) / 256, 256, 0, stream>>>(normw, inidx, invadj, numn, demands,
                                                  supply, wgt, srcn, totA);

    float* cur = totA; float* nxt = totB;
    for (int it = 0; it < 10; ++it) {
        k_flowT<<<(BN_ + 255) / 256, 256, 0, stream>>>(cur, wgt, srcn, supply, nxt);
        float* tmp = cur; cur = nxt; nxt = tmp;
    }

    dim3 gred((NK_ + 255) / 256, B_);
    k_dualred<<<gred, 256, 0, stream>>>(el, dv, adj, numn, normw, cur, acc);
    k_final<<<1, 64, 0, stream>>>(acc, (float*)d_out);
}

// Round 11
// 343.972 us; speedup vs baseline: 2.0479x; 1.0730x over previous
//
#include <hip/hip_runtime.h>
#include <math.h>

#define B_ 4
#define N_ 5000
#define K_ 16
#define L_ 3
#define F_ 2
#define E_ 32
#define D_ 64
#define H_ 4
#define BN_ (B_*N_)          /* 20000 */
#define NK_ (N_*K_)          /* 80000 */
#define BIG_ 1.0e9f
#define RS_ 68               /* padded LDS row stride (floats) */

// ---------------- zero the accumulators -------------------------------------
__global__ void k_zero(float* __restrict__ acc) {
    if (threadIdx.x < 192) acc[threadIdx.x] = 0.f;
}

// ---------------- encoder: h = [emb_norm, feat] @ enc_W + enc_b -------------
__global__ __launch_bounds__(256) void k_encode(
    const float* __restrict__ embed, const float* __restrict__ feat,
    const float* __restrict__ encW, const float* __restrict__ encb,
    float* __restrict__ h)
{
    int wave = threadIdx.x >> 6;
    int lane = threadIdx.x & 63;
    int node = blockIdx.x * 4 + wave;      // b*N+n  in [0,20000)
    int n = node % N_;

    float e = (lane < E_) ? embed[(size_t)n * E_ + lane] : 0.f;
    float ss = e * e;
    #pragma unroll
    for (int m = 32; m >= 1; m >>= 1) ss += __shfl_xor(ss, m, 64);
    float scale = 1.f / fmaxf(sqrtf(ss), 1.f);

    float inval = (lane < E_) ? e * scale
                : (lane < E_ + F_) ? feat[(size_t)node * F_ + (lane - E_)]
                : 0.f;

    float acc = encb[lane];
    #pragma unroll
    for (int i = 0; i < E_ + F_; ++i)
        acc = fmaf(__shfl(inval, i, 64), encW[i * D_ + lane], acc);
    h[(size_t)node * D_ + lane] = acc;
}

// ---------------- bf16-packed weight helpers --------------------------------
__device__ __forceinline__ float blo(unsigned u) { return __uint_as_float(u << 16); }
__device__ __forceinline__ float bhi(unsigned u) { return __uint_as_float(u & 0xffff0000u); }

// pack two fp32 to bf16 (RNE): lo -> bits 15:0, hi -> bits 31:16
__device__ __forceinline__ unsigned pack_bf16(float lo, float hi) {
    unsigned ul = __float_as_uint(lo);
    unsigned uh = __float_as_uint(hi);
    ul = (ul + 0x7fffu + ((ul >> 16) & 1u)) >> 16;
    uh = (uh + 0x7fffu + ((uh >> 16) & 1u)) & 0xffff0000u;
    return uh | ul;
}

// stage 64x64 fp32 W -> LDS packed u32[32][64]: dst[k2*64+c] = (W[2k2][c], W[2k2+1][c])
__device__ __forceinline__ void stageWB(unsigned* dst, const float* __restrict__ src, int tx)
{
    #pragma unroll
    for (int i = tx; i < 2048; i += 256) {
        int k2 = i >> 6, c = i & 63;
        dst[i] = pack_bf16(src[(2 * k2) * 64 + c], src[(2 * k2 + 1) * 64 + c]);
    }
}

// transposed stage for the y-pass: dst[c2*64+c] = (Wk[c][2c2], Wk[c][2c2+1])
__device__ __forceinline__ void stageWKT(unsigned* dst, const float* __restrict__ src, int tx)
{
    #pragma unroll
    for (int i = tx; i < 2048; i += 256) {
        int c2 = i >> 6, c = i & 63;
        dst[i] = pack_bf16(src[c * 64 + 2 * c2], src[c * 64 + 2 * c2 + 1]);
    }
}

// ---------- per-thread row GEMM: 1 row x 4 cols, A fp32 (LDS), W bf16-packed
__device__ __forceinline__ void mmrow_gB(
    const float* Arow, const unsigned* Wp, int c0, float acc[4])
{
    #pragma unroll 4
    for (int k2 = 0; k2 < 32; k2 += 2) {
        float4 a = *(const float4*)&Arow[2 * k2];          // k = 2k2 .. 2k2+3
        uint4 wA = *(const uint4*)&Wp[k2 * 64 + c0];       // k=2k2(lo), 2k2+1(hi)
        uint4 wB = *(const uint4*)&Wp[(k2 + 1) * 64 + c0]; // k=2k2+2(lo), 2k2+3(hi)
        acc[0] = fmaf(a.x, blo(wA.x), acc[0]); acc[1] = fmaf(a.x, blo(wA.y), acc[1]);
        acc[2] = fmaf(a.x, blo(wA.z), acc[2]); acc[3] = fmaf(a.x, blo(wA.w), acc[3]);
        acc[0] = fmaf(a.y, bhi(wA.x), acc[0]); acc[1] = fmaf(a.y, bhi(wA.y), acc[1]);
        acc[2] = fmaf(a.y, bhi(wA.z), acc[2]); acc[3] = fmaf(a.y, bhi(wA.w), acc[3]);
        acc[0] = fmaf(a.z, blo(wB.x), acc[0]); acc[1] = fmaf(a.z, blo(wB.y), acc[1]);
        acc[2] = fmaf(a.z, blo(wB.z), acc[2]); acc[3] = fmaf(a.z, blo(wB.w), acc[3]);
        acc[0] = fmaf(a.w, bhi(wB.x), acc[0]); acc[1] = fmaf(a.w, bhi(wB.y), acc[1]);
        acc[2] = fmaf(a.w, bhi(wB.z), acc[2]); acc[3] = fmaf(a.w, bhi(wB.w), acc[3]);
    }
}

// combined 3-source A row (w0*A0 + w1*A1 + w2*A2) @ W(bf16-packed)
__device__ __forceinline__ void mmrow_3cB(
    const float* A0, const float* A1, const float* A2,
    float w0, float w1, float w2,
    const unsigned* Wp, int c0, float acc[4])
{
    #pragma unroll 4
    for (int k2 = 0; k2 < 32; k2 += 2) {
        float4 a0 = *(const float4*)&A0[2 * k2];
        float4 a1 = *(const float4*)&A1[2 * k2];
        float4 a2 = *(const float4*)&A2[2 * k2];
        float ax = fmaf(w0, a0.x, fmaf(w1, a1.x, w2 * a2.x));
        float ay = fmaf(w0, a0.y, fmaf(w1, a1.y, w2 * a2.y));
        float az = fmaf(w0, a0.z, fmaf(w1, a1.z, w2 * a2.z));
        float aw = fmaf(w0, a0.w, fmaf(w1, a1.w, w2 * a2.w));
        uint4 wA = *(const uint4*)&Wp[k2 * 64 + c0];
        uint4 wB = *(const uint4*)&Wp[(k2 + 1) * 64 + c0];
        acc[0] = fmaf(ax, blo(wA.x), acc[0]); acc[1] = fmaf(ax, blo(wA.y), acc[1]);
        acc[2] = fmaf(ax, blo(wA.z), acc[2]); acc[3] = fmaf(ax, blo(wA.w), acc[3]);
        acc[0] = fmaf(ay, bhi(wA.x), acc[0]); acc[1] = fmaf(ay, bhi(wA.y), acc[1]);
        acc[2] = fmaf(ay, bhi(wA.z), acc[2]); acc[3] = fmaf(ay, bhi(wA.w), acc[3]);
        acc[0] = fmaf(az, blo(wB.x), acc[0]); acc[1] = fmaf(az, blo(wB.y), acc[1]);
        acc[2] = fmaf(az, blo(wB.z), acc[2]); acc[3] = fmaf(az, blo(wB.w), acc[3]);
        acc[0] = fmaf(aw, bhi(wB.x), acc[0]); acc[1] = fmaf(aw, bhi(wB.y), acc[1]);
        acc[2] = fmaf(aw, bhi(wB.z), acc[2]); acc[3] = fmaf(aw, bhi(wB.w), acc[3]);
    }
}

// ================= fully fused graph layer (bf16-packed weights) ============
// 16 nodes/block, 256 threads: thread = (row = tx>>4, cols c0=4*(tx&15)).
// Weight slots are 8KB each (u32-packed bf16) -> LDS ~41KB -> 3 blocks/CU.
__global__ __launch_bounds__(256, 3) void k_layer(
    const float* __restrict__ hin, float* __restrict__ hout,
    const int* __restrict__ neigh, const int* __restrict__ numn,
    const float* __restrict__ nbW, const float* __restrict__ Wq,
    const float* __restrict__ Wk, const float* __restrict__ Wv,
    const float* __restrict__ Wo,
    const float* __restrict__ gWz, const float* __restrict__ gUz, const float* __restrict__ gbz,
    const float* __restrict__ gWr, const float* __restrict__ gUr, const float* __restrict__ gbr,
    const float* __restrict__ gWh, const float* __restrict__ gUh, const float* __restrict__ gbh)
{
    __shared__ __align__(16) unsigned wp0[2048];   // 8KB W slot A (bf16 packed)
    __shared__ __align__(16) unsigned wp1[2048];   // 8KB W slot B
    __shared__ __align__(16) float sM[3][16 * RS_];// mean->state tiles
    __shared__ __align__(16) float sH[16 * RS_];   // h tile
    __shared__ __align__(16) float sX[16 * RS_];   // q -> ao -> x tile
    __shared__ int   sIdx[3][256];                 // neighbor ids, [t][k*16+row]

    int tx = threadIdx.x;
    int row = tx >> 4, cg = tx & 15, c0 = cg * 4;
    int g = blockIdx.x * 16 + row;          // node id (grid exact: 1250*16=20000)
    int b = g / N_;
    int pad = numn[b];
    const float4* hb4 = (const float4*)(hin + (size_t)b * N_ * D_);

    // ---- phase 0: stage Wq|nbW, h rows, neighbor ids ----
    stageWB(wp0, Wq, tx);
    stageWB(wp1, nbW, tx);
    *(float4*)&sH[row * RS_ + c0] = *(const float4*)&hin[(size_t)g * 64 + c0];
    #pragma unroll
    for (int t = 0; t < 3; ++t)
        sIdx[t][cg * 16 + row] = neigh[((size_t)t * BN_ + g) * K_ + cg];
    __syncthreads();

    // q = h_row @ Wq -> sX row (needed in full by the y-pass)
    {
        float qv[4] = {0.f, 0.f, 0.f, 0.f};
        mmrow_gB(&sH[row * RS_], wp0, c0, qv);
        *(float4*)&sX[row * RS_ + c0] = make_float4(qv[0], qv[1], qv[2], qv[3]);
    }

    // ---- gather-mean + states for all 3 neighborhoods (row-local) ----
    #pragma unroll 1
    for (int t = 0; t < 3; ++t) {
        float4 s = make_float4(0.f, 0.f, 0.f, 0.f);
        int cnt = 0;
        #pragma unroll
        for (int k = 0; k < K_; ++k) {
            int idx = sIdx[t][k * 16 + row];
            if (idx != pad) {
                float4 v = hb4[(size_t)idx * 16 + cg];
                s.x += v.x; s.y += v.y; s.z += v.z; s.w += v.w;
                cnt++;
            }
        }
        float inv = 1.f / fmaxf((float)cnt, 1.f);
        *(float4*)&sM[t][row * RS_ + c0] =
            make_float4(s.x * inv, s.y * inv, s.z * inv, s.w * inv);

        float sr[4] = {0.f, 0.f, 0.f, 0.f};
        mmrow_gB(&sM[t][row * RS_], wp1, c0, sr);     // mean @ nbW
        *(float4*)&sM[t][row * RS_ + c0] =
            make_float4(tanhf(sr[0]), tanhf(sr[1]), tanhf(sr[2]), tanhf(sr[3]));
    }
    __syncthreads();

    // ---- phase 1: Wk^T (packed) | Wv ----
    stageWKT(wp0, Wk, tx);
    stageWB(wp1, Wv, tx);
    __syncthreads();

    // y-pass: y[h][r] = sum_{c' in head h} q[c'] * Wk[c0+r][c']
    float y[4][4] = {};
    #pragma unroll
    for (int c2 = 0; c2 < 32; c2 += 2) {              // c' = 2c2 .. 2c2+3
        float4 q4 = *(const float4*)&sX[row * RS_ + 2 * c2];
        const int h = c2 >> 3;                        // head (compile-time)
        uint4 wA = *(const uint4*)&wp0[c2 * 64 + c0];
        uint4 wB = *(const uint4*)&wp0[(c2 + 1) * 64 + c0];
        y[h][0] = fmaf(q4.x, blo(wA.x), y[h][0]); y[h][1] = fmaf(q4.x, blo(wA.y), y[h][1]);
        y[h][2] = fmaf(q4.x, blo(wA.z), y[h][2]); y[h][3] = fmaf(q4.x, blo(wA.w), y[h][3]);
        y[h][0] = fmaf(q4.y, bhi(wA.x), y[h][0]); y[h][1] = fmaf(q4.y, bhi(wA.y), y[h][1]);
        y[h][2] = fmaf(q4.y, bhi(wA.z), y[h][2]); y[h][3] = fmaf(q4.y, bhi(wA.w), y[h][3]);
        y[h][0] = fmaf(q4.z, blo(wB.x), y[h][0]); y[h][1] = fmaf(q4.z, blo(wB.y), y[h][1]);
        y[h][2] = fmaf(q4.z, blo(wB.z), y[h][2]); y[h][3] = fmaf(q4.z, blo(wB.w), y[h][3]);
        y[h][0] = fmaf(q4.w, bhi(wB.x), y[h][0]); y[h][1] = fmaf(q4.w, bhi(wB.y), y[h][1]);
        y[h][2] = fmaf(q4.w, bhi(wB.z), y[h][2]); y[h][3] = fmaf(q4.w, bhi(wB.w), y[h][3]);
    }

    // scores p[t][h] = s_t . y_h (reduce over the 16-lane row group), softmax
    float w0, w1, w2;
    {
        float pt[3][4];
        #pragma unroll
        for (int t = 0; t < 3; ++t) {
            float4 st = *(const float4*)&sM[t][row * RS_ + c0];
            #pragma unroll
            for (int h = 0; h < 4; ++h) {
                float pp = st.x * y[h][0] + st.y * y[h][1]
                         + st.z * y[h][2] + st.w * y[h][3];
                pp += __shfl_xor(pp, 1, 64);
                pp += __shfl_xor(pp, 2, 64);
                pp += __shfl_xor(pp, 4, 64);
                pp += __shfl_xor(pp, 8, 64);
                pt[t][h] = pp * 0.25f;                // / sqrt(dh=16)
            }
        }
        int ho = cg >> 2;                             // head of this thread's cols
        float p0 = (ho == 0) ? pt[0][0] : (ho == 1) ? pt[0][1] : (ho == 2) ? pt[0][2] : pt[0][3];
        float p1 = (ho == 0) ? pt[1][0] : (ho == 1) ? pt[1][1] : (ho == 2) ? pt[1][2] : pt[1][3];
        float p2 = (ho == 0) ? pt[2][0] : (ho == 1) ? pt[2][1] : (ho == 2) ? pt[2][2] : pt[2][3];
        float mx = fmaxf(p0, fmaxf(p1, p2));
        float e0 = expf(p0 - mx), e1 = expf(p1 - mx), e2 = expf(p2 - mx);
        float inv = 1.f / (e0 + e1 + e2);
        w0 = e0 * inv; w1 = e1 * inv; w2 = e2 * inv;
    }

    // ao = (w0*s0 + w1*s1 + w2*s2) @ Wv  -> sX (q is dead)
    {
        float ao[4] = {0.f, 0.f, 0.f, 0.f};
        mmrow_3cB(&sM[0][row * RS_], &sM[1][row * RS_], &sM[2][row * RS_],
                  w0, w1, w2, wp1, c0, ao);
        *(float4*)&sX[row * RS_ + c0] = make_float4(ao[0], ao[1], ao[2], ao[3]);
    }
    __syncthreads();

    // ---- phase 2: Wo|gWz; x = tanh(ao@Wo); az = x@gWz ----
    stageWB(wp0, Wo, tx);
    stageWB(wp1, gWz, tx);
    __syncthreads();
    float xr[4] = {0.f, 0.f, 0.f, 0.f};
    mmrow_gB(&sX[row * RS_], wp0, c0, xr);            // ao @ Wo
    *(float4*)&sX[row * RS_ + c0] =
        make_float4(tanhf(xr[0]), tanhf(xr[1]), tanhf(xr[2]), tanhf(xr[3]));
    float az[4] = {0.f, 0.f, 0.f, 0.f};
    mmrow_gB(&sX[row * RS_], wp1, c0, az);            // x @ gWz (own row, same wave)
    __syncthreads();

    // ---- phase 3: gUz|gWr ----
    stageWB(wp0, gUz, tx);
    stageWB(wp1, gWr, tx);
    __syncthreads();
    mmrow_gB(&sH[row * RS_], wp0, c0, az);            // += h @ gUz
    float ar[4] = {0.f, 0.f, 0.f, 0.f};
    mmrow_gB(&sX[row * RS_], wp1, c0, ar);            // x @ gWr
    __syncthreads();

    // ---- phase 4: gUr|gWh ----
    stageWB(wp0, gUr, tx);
    stageWB(wp1, gWh, tx);
    __syncthreads();
    mmrow_gB(&sH[row * RS_], wp0, c0, ar);            // += h @ gUr

    float4 bzv = *(const float4*)&gbz[c0];
    float4 brv = *(const float4*)&gbr[c0];
    float4 hv  = *(const float4*)&sH[row * RS_ + c0];
    float z[4], rr[4];
    z[0] = 1.f / (1.f + expf(-(az[0] + bzv.x)));
    z[1] = 1.f / (1.f + expf(-(az[1] + bzv.y)));
    z[2] = 1.f / (1.f + expf(-(az[2] + bzv.z)));
    z[3] = 1.f / (1.f + expf(-(az[3] + bzv.w)));
    rr[0] = 1.f / (1.f + expf(-(ar[0] + brv.x)));
    rr[1] = 1.f / (1.f + expf(-(ar[1] + brv.y)));
    rr[2] = 1.f / (1.f + expf(-(ar[2] + brv.z)));
    rr[3] = 1.f / (1.f + expf(-(ar[3] + brv.w)));
    *(float4*)&sM[0][row * RS_ + c0] =                // rh tile (sM[0] is dead)
        make_float4(rr[0] * hv.x, rr[1] * hv.y, rr[2] * hv.z, rr[3] * hv.w);

    float ah[4] = {0.f, 0.f, 0.f, 0.f};
    mmrow_gB(&sX[row * RS_], wp1, c0, ah);            // x @ gWh
    __syncthreads();

    // ---- phase 5: gUh ----
    stageWB(wp0, gUh, tx);
    __syncthreads();
    mmrow_gB(&sM[0][row * RS_], wp0, c0, ah);         // += rh @ gUh

    float4 bhv = *(const float4*)&gbh[c0];
    float o0 = (1.f - z[0]) * hv.x + z[0] * tanhf(ah[0] + bhv.x);
    float o1 = (1.f - z[1]) * hv.y + z[1] * tanhf(ah[1] + bhv.y);
    float o2 = (1.f - z[2]) * hv.z + z[2] * tanhf(ah[2] + bhv.z);
    float o3 = (1.f - z[3]) * hv.w + z[3] * tanhf(ah[3] + bhv.w);
    *(float4*)&hout[(size_t)g * 64 + c0] = make_float4(o0, o1, o2, o3);
}

// ---------------- edge projection ------------------------------------------
__global__ __launch_bounds__(256) void k_edgeproj(
    const float* __restrict__ h, const float* __restrict__ W1,
    float* __restrict__ P)
{
    int wave = threadIdx.x >> 6;
    int lane = threadIdx.x & 63;
    int node = blockIdx.x * 4 + wave;      // < 20000

    float hval = h[(size_t)node * D_ + lane];
    const float* wp = (lane < 32) ? (W1 + lane) : (W1 + 64 * 32 + (lane - 32));
    float acc = 0.f;
    #pragma unroll 8
    for (int i = 0; i < D_; ++i)
        acc = fmaf(__shfl(hval, i, 64), wp[i * 32], acc);
    P[(size_t)node * D_ + lane] = acc;
}

// ---------------- edge decoder (light) --------------------------------------
__global__ __launch_bounds__(256) void k_decoder2(
    const float* __restrict__ P, const int* __restrict__ adj,
    const float* __restrict__ b1, const float* __restrict__ W2,
    const float* __restrict__ b2, const int* __restrict__ num_nodes,
    float* __restrict__ nw)
{
    int half = threadIdx.x >> 5;   // 0..7
    int j    = threadIdx.x & 31;
    float bias = b1[j], w2 = W2[j], b2v = b2[0];

    #pragma unroll 1
    for (int p = 0; p < 16; ++p) {
        int e = blockIdx.x * 128 + p * 8 + half;  // edge id < 320000
        int node = e >> 4;                        // b*N+n
        int b = node / N_;
        int a = adj[e];
        int pad = num_nodes[b];
        float own = P[(size_t)node * D_ + j];
        bool pd = (a == pad);
        float nbr = pd ? 0.f : P[((size_t)b * N_ + a) * D_ + 32 + j];
        float am = pd ? 0.f : 1.f;
        float t = tanhf(bias + am * own + nbr);
        float part = t * w2;
        #pragma unroll
        for (int m = 1; m < 32; m <<= 1) part += __shfl_xor(part, m, 64);
        if (j == 0) nw[e] = part + b2v;
    }
}

// ---------------- dual vars (per node scalar) + dual_demand -----------------
__global__ __launch_bounds__(256) void k_dualvars(
    const float* __restrict__ h, const float* __restrict__ W1,
    const float* __restrict__ b1, const float* __restrict__ W2,
    const float* __restrict__ b2, const float* __restrict__ demands,
    const int* __restrict__ num_nodes,
    float* __restrict__ dv, float* __restrict__ acc_out)
{
    __shared__ float sW1[D_ * 32];
    __shared__ float sW2[32];
    __shared__ float sPart[8];
    for (int i = threadIdx.x; i < D_ * 32; i += 256) sW1[i] = W1[i];
    if (threadIdx.x < 32) sW2[threadIdx.x] = W2[threadIdx.x];
    __syncthreads();

    int half = threadIdx.x >> 5;
    int j    = threadIdx.x & 31;
    int b = (blockIdx.x * 40) / N_;
    float bias = b1[j], b2v = b2[0];
    float local = 0.f;

    #pragma unroll 1
    for (int p = 0; p < 5; ++p) {
        int node = blockIdx.x * 40 + p * 8 + half;    // < 20000
        const float* hp = h + (size_t)node * D_;
        float h0 = hp[j], h1 = hp[j + 32];
        float acc = bias;
        #pragma unroll 8
        for (int i = 0; i < 32; ++i) {
            acc = fmaf(__shfl(h0, i, 32), sW1[i * 32 + j],        acc);
            acc = fmaf(__shfl(h1, i, 32), sW1[(i + 32) * 32 + j], acc);
        }
        float t = tanhf(acc);
        float part = t * sW2[j];
        #pragma unroll
        for (int m = 1; m < 32; m <<= 1) part += __shfl_xor(part, m, 64);
        if (j == 0) {
            float v = part + b2v;
            dv[node] = v;
            local += v * demands[node];
        }
    }
    if (j == 0) sPart[half] = local;
    __syncthreads();
    if (threadIdx.x == 0) {
        float s = 0.f;
        #pragma unroll
        for (int i = 0; i < 8; ++i) s += sPart[i];
        atomicAdd(&acc_out[(b * 3 + 2) * 16], s);
    }
}

// ---------------- dest softmax over permuted groups -------------------------
__global__ void k_dest(
    const float* __restrict__ nw, const int* __restrict__ in_idx,
    const int* __restrict__ inv_adj, const int* __restrict__ num_nodes,
    float* __restrict__ dest)
{
    int t = blockIdx.x * 256 + threadIdx.x;
    if (t >= BN_) return;
    int b = t / N_;
    int pad = num_nodes[b];
    float vals[K_]; float mx = -INFINITY;
    #pragma unroll
    for (int k = 0; k < K_; ++k) {
        int jj = in_idx[(size_t)t * K_ + k];
        float g = nw[(size_t)b * NK_ + jj];
        float im = (inv_adj[(size_t)t * K_ + k] == pad) ? 1.f : 0.f;
        float v = g - BIG_ * im;
        vals[k] = v; mx = fmaxf(mx, v);
    }
    float s = 0.f;
    #pragma unroll
    for (int k = 0; k < K_; ++k) { vals[k] = expf(vals[k] - mx); s += vals[k]; }
    float invs = 1.f / s;
    #pragma unroll
    for (int k = 0; k < K_; ++k) dest[(size_t)t * K_ + k] = vals[k] * invs;
}

// ---------------- normalized_weights ----------------------------------------
__global__ void k_normw(
    const float* __restrict__ nw, const float* __restrict__ dest,
    const int* __restrict__ rev, const int* __restrict__ adj,
    const int* __restrict__ num_nodes,
    float* __restrict__ normw)
{
    int t = blockIdx.x * 256 + threadIdx.x;
    if (t >= BN_) return;
    int b = t / N_;
    int pad = num_nodes[b];
    float vals[K_]; float mx = -INFINITY;
    #pragma unroll
    for (int k = 0; k < K_; ++k) {
        size_t e = (size_t)t * K_ + k;
        float v = nw[e] * dest[(size_t)b * NK_ + rev[e]];
        float m = (adj[e] == pad) ? 1.f : 0.f;
        v -= BIG_ * m;
        vals[k] = v; mx = fmaxf(mx, v);
    }
    float s = 0.f;
    #pragma unroll
    for (int k = 0; k < K_; ++k) { vals[k] = expf(vals[k] - mx); s += vals[k]; }
    float invs = 1.f / s;
    #pragma unroll
    for (int k = 0; k < K_; ++k)
        normw[(size_t)t * K_ + k] = vals[k] * invs;
}

// ---------------- flow prep: supply, iteration weights + source nodes -------
__global__ void k_prep(
    const float* __restrict__ normw, const int* __restrict__ in_idx,
    const int* __restrict__ inv_adj, const int* __restrict__ num_nodes,
    const float* __restrict__ demands,
    float* __restrict__ supply, float* __restrict__ wgt, int* __restrict__ srcn,
    float* __restrict__ tot0)
{
    int t = blockIdx.x * 256 + threadIdx.x;
    if (t >= BN_) return;
    int b = t / N_;
    int pad = num_nodes[b];
    float sup = fmaxf(-demands[t], 0.f);
    supply[t] = sup;
    tot0[t] = sup;
    #pragma unroll
    for (int k = 0; k < K_; ++k) {
        size_t e = (size_t)t * K_ + k;
        int j = in_idx[e];
        bool valid = (inv_adj[e] != pad);
        wgt[e] = valid ? normw[(size_t)b * NK_ + j] : 0.f;
        srcn[e] = b * N_ + (j >> 4);
    }
}

// ---------------- one tot-space flow step (80KB state) ----------------------
__global__ void k_flowT(
    const float* __restrict__ totIn, const float* __restrict__ wgt,
    const int* __restrict__ srcn, const float* __restrict__ supply,
    float* __restrict__ totOut)
{
    int t = blockIdx.x * 256 + threadIdx.x;
    if (t >= BN_) return;
    float s = supply[t];
    #pragma unroll
    for (int k = 0; k < K_; ++k) {
        size_t e = (size_t)t * K_ + k;
        s = fmaf(wgt[e], totIn[srcn[e]], s);
    }
    totOut[t] = s;
}

// ---------------- dual iterations + both cost reductions --------------------
__global__ __launch_bounds__(256) void k_dualred(
    const float* __restrict__ el, const float* __restrict__ dv,
    const int* __restrict__ adj, const int* __restrict__ num_nodes,
    const float* __restrict__ normw, const float* __restrict__ tot10,
    float* __restrict__ acc_out)
{
    int b = blockIdx.y;
    int ein = blockIdx.x * 256 + threadIdx.x;
    float c0 = 0.f, c1 = 0.f;
    if (ein < NK_) {
        size_t e = (size_t)b * NK_ + ein;
        int pad = num_nodes[b];
        int node = b * N_ + (ein >> 4);
        int a = adj[e];
        float am = (a == pad) ? 0.f : 1.f;
        float dtr = (a == pad) ? 0.f : dv[(size_t)b * N_ + a];
        float d = dtr - am * dv[node];
        float l = el[e];
        float f = 0.f, ac = 0.f;
        #pragma unroll
        for (int it = 0; it < 10; ++it) {
            float g = 2.f * l * f + d;
            ac = 0.9f * ac + 0.01f * g;
            f = fmaxf(f - ac, 0.f) * am;
        }
        float fl = normw[e] * tot10[node];
        c0 = l * fl * fl;          // flow_cost term
        c1 = l * f * f + d * f;    // dual flow term
    }
    #pragma unroll
    for (int m = 1; m < 64; m <<= 1) { c0 += __shfl_xor(c0, m, 64); c1 += __shfl_xor(c1, m, 64); }
    __shared__ float s0[4], s1[4];
    int wave = threadIdx.x >> 6, lane = threadIdx.x & 63;
    if (lane == 0) { s0[wave] = c0; s1[wave] = c1; }
    __syncthreads();
    if (threadIdx.x == 0) {
        atomicAdd(&acc_out[(b * 3 + 0) * 16], s0[0] + s0[1] + s0[2] + s0[3]);
        atomicAdd(&acc_out[(b * 3 + 1) * 16], s1[0] + s1[1] + s1[2] + s1[3]);
    }
}

// ---------------- finalize --------------------------------------------------
__global__ void k_final(const float* __restrict__ acc, float* __restrict__ out) {
    int b = threadIdx.x;
    if (b < B_)
        out[b] = acc[(b * 3 + 0) * 16] - acc[(b * 3 + 1) * 16] + acc[(b * 3 + 2) * 16];
}

extern "C" void kernel_launch(void* const* d_in, const int* in_sizes, int n_in,
                              void* d_out, int out_size, void* d_ws, size_t ws_size,
                              hipStream_t stream)
{
    const float* demands = (const float*)d_in[0];
    const float* feat    = (const float*)d_in[1];
    const float* el      = (const float*)d_in[2];
    const float* embed   = (const float*)d_in[3];
    const float* encW    = (const float*)d_in[4];
    const float* encb    = (const float*)d_in[5];
    const float* nbW     = (const float*)d_in[6];
    const float* Wq      = (const float*)d_in[7];
    const float* Wk      = (const float*)d_in[8];
    const float* Wv      = (const float*)d_in[9];
    const float* Wo      = (const float*)d_in[10];
    const float* gWz     = (const float*)d_in[11];
    const float* gUz     = (const float*)d_in[12];
    const float* gbz     = (const float*)d_in[13];
    const float* gWr     = (const float*)d_in[14];
    const float* gUr     = (const float*)d_in[15];
    const float* gbr     = (const float*)d_in[16];
    const float* gWh     = (const float*)d_in[17];
    const float* gUh     = (const float*)d_in[18];
    const float* gbh     = (const float*)d_in[19];
    const float* decW1   = (const float*)d_in[20];
    const float* decb1   = (const float*)d_in[21];
    const float* decW2   = (const float*)d_in[22];
    const float* decb2   = (const float*)d_in[23];
    const float* dualW1  = (const float*)d_in[24];
    const float* dualb1  = (const float*)d_in[25];
    const float* dualW2  = (const float*)d_in[26];
    const float* dualb2  = (const float*)d_in[27];
    const int* adj       = (const int*)d_in[28];
    const int* invadj    = (const int*)d_in[29];
    const int* neigh     = (const int*)d_in[30];
    const int* inidx     = (const int*)d_in[31];
    const int* revidx    = (const int*)d_in[32];
    const int* numn      = (const int*)d_in[33];

    // workspace (floats), ~17MB
    float* ws     = (float*)d_ws;
    float* h0     = ws;                   // 1,280,000
    float* h1     = ws + 1280000;         // 1,280,000 (ping-pong; P after layers)
    float* nw     = ws + 2560000;         // 320,000
    float* dest   = ws + 2880000;         // 320,000
    float* normw  = ws + 3200000;         // 320,000
    float* wgt    = ws + 3520000;         // 320,000
    int*   srcn   = (int*)(ws + 3840000); // 320,000 ints
    float* totA   = ws + 4160000;         // 20,000
    float* totB   = ws + 4180000;         // 20,000
    float* supply = ws + 4200000;         // 20,000
    float* dv     = ws + 4220000;         // 20,000
    float* P      = h1;                   // reuse (h1 dead after layer 1)
    float* acc    = ws + 4240000;         // 192

    k_zero<<<1, 256, 0, stream>>>(acc);
    k_encode<<<BN_ / 4, 256, 0, stream>>>(embed, feat, encW, encb, h0);

    // layer 0: h0 -> h1 ; layer 1: h1 -> h0  (gathers must read pre-layer h)
    k_layer<<<BN_ / 16, 256, 0, stream>>>(h0, h1, neigh, numn, nbW, Wq, Wk, Wv, Wo,
                                          gWz, gUz, gbz, gWr, gUr, gbr, gWh, gUh, gbh);
    k_layer<<<BN_ / 16, 256, 0, stream>>>(h1, h0, neigh, numn, nbW, Wq, Wk, Wv, Wo,
                                          gWz, gUz, gbz, gWr, gUr, gbr, gWh, gUh, gbh);
    float* h = h0;

    k_edgeproj<<<BN_ / 4, 256, 0, stream>>>(h, decW1, P);
    k_decoder2<<<(B_ * NK_) / 128, 256, 0, stream>>>(P, adj, decb1, decW2, decb2, numn, nw);
    k_dualvars<<<BN_ / 40, 256, 0, stream>>>(h, dualW1, dualb1, dualW2, dualb2, demands, numn, dv, acc);
    k_dest<<<(BN_ + 255) / 256, 256, 0, stream>>>(nw, inidx, invadj, numn, dest);
    k_normw<<<(BN_ + 255) / 256, 256, 0, stream>>>(nw, dest, revidx, adj, numn, normw);
    k_prep<<<(BN_ + 255) / 256, 256, 0, stream>>>(normw, inidx, invadj, numn, demands,
                                                  supply, wgt, srcn, totA);

    float* cur = totA; float* nxt = totB;
    for (int it = 0; it < 10; ++it) {
        k_flowT<<<(BN_ + 255) / 256, 256, 0, stream>>>(cur, wgt, srcn, supply, nxt);
        float* tmp = cur; cur = nxt; nxt = tmp;
    }

    dim3 gred((NK_ + 255) / 256, B_);
    k_dualred<<<gred, 256, 0, stream>>>(el, dv, adj, numn, normw, cur, acc);
    k_final<<<1, 64, 0, stream>>>(acc, (float*)d_out);
}

// Round 12
// 265.834 us; speedup vs baseline: 2.6498x; 1.2939x over previous
//
#include <hip/hip_runtime.h>
#include <math.h>

#define B_ 4
#define N_ 5000
#define K_ 16
#define L_ 3
#define F_ 2
#define E_ 32
#define D_ 64
#define H_ 4
#define BN_ (B_*N_)          /* 20000 */
#define NK_ (N_*K_)          /* 80000 */
#define BIG_ 1.0e9f
#define RS_ 68               /* padded LDS tile row stride (floats) */

typedef __attribute__((ext_vector_type(8))) short s8v;   // bf16x8 MFMA frag
typedef __attribute__((ext_vector_type(4))) float f4v;   // fp32x4 accum

union FU { uint4 u; s8v s; };

// ---------------- zero the accumulators -------------------------------------
__global__ void k_zero(float* __restrict__ acc) {
    if (threadIdx.x < 192) acc[threadIdx.x] = 0.f;
}

// ---------------- encoder: h = [emb_norm, feat] @ enc_W + enc_b -------------
__global__ __launch_bounds__(256) void k_encode(
    const float* __restrict__ embed, const float* __restrict__ feat,
    const float* __restrict__ encW, const float* __restrict__ encb,
    float* __restrict__ h)
{
    int wave = threadIdx.x >> 6;
    int lane = threadIdx.x & 63;
    int node = blockIdx.x * 4 + wave;      // b*N+n  in [0,20000)
    int n = node % N_;

    float e = (lane < E_) ? embed[(size_t)n * E_ + lane] : 0.f;
    float ss = e * e;
    #pragma unroll
    for (int m = 32; m >= 1; m >>= 1) ss += __shfl_xor(ss, m, 64);
    float scale = 1.f / fmaxf(sqrtf(ss), 1.f);

    float inval = (lane < E_) ? e * scale
                : (lane < E_ + F_) ? feat[(size_t)node * F_ + (lane - E_)]
                : 0.f;

    float acc = encb[lane];
    #pragma unroll
    for (int i = 0; i < E_ + F_; ++i)
        acc = fmaf(__shfl(inval, i, 64), encW[i * D_ + lane], acc);
    h[(size_t)node * D_ + lane] = acc;
}

// ---------------- bf16 pack (RNE) -------------------------------------------
__device__ __forceinline__ unsigned pack_bf16(float lo, float hi) {
    unsigned ul = __float_as_uint(lo);
    unsigned uh = __float_as_uint(hi);
    ul = (ul + 0x7fffu + ((ul >> 16) & 1u)) >> 16;
    uh = (uh + 0x7fffu + ((uh >> 16) & 1u)) & 0xffff0000u;
    return uh | ul;
}

// stage 64x64 fp32 W -> LDS B-fragment order (bf16 packed):
// frag group f = s*4+w (k-step s, col-tile w); lane holds
// W[k=32s+8*(lane>>4)+e][col=16w+(lane&15)], e=0..7 as 4 u32 (k-pairs).
__device__ __forceinline__ void stageWF(unsigned* dst, const float* __restrict__ src, int tx)
{
    #pragma unroll
    for (int j = tx; j < 2048; j += 256) {
        int fgrp = j >> 8;
        int li = j & 255;
        int e2 = li >> 6;            // 0..3
        int lane = li & 63;
        int s = fgrp >> 2, w = fgrp & 3;
        int k = 32 * s + 8 * (lane >> 4) + 2 * e2;
        int c = 16 * w + (lane & 15);
        dst[fgrp * 256 + lane * 4 + e2] = pack_bf16(src[k * 64 + c], src[(k + 1) * 64 + c]);
    }
}

// B-fragment read: contiguous 16B per lane, conflict-free
__device__ __forceinline__ s8v bfrag(const unsigned* wf, int s, int w, int lane)
{
    FU f;
    f.u = *(const uint4*)&wf[((s * 4 + w) * 64 + lane) * 4];
    return f.s;
}

// A-fragment from fp32 tile (stride RS_): row=lane&15, k=32s+8*(lane>>4)+e
__device__ __forceinline__ s8v afragS(const float* T, int lane, int s)
{
    int row = lane & 15;
    int kb = 32 * s + 8 * (lane >> 4);
    float4 a = *(const float4*)&T[row * RS_ + kb];
    float4 b = *(const float4*)&T[row * RS_ + kb + 4];
    FU f;
    f.u.x = pack_bf16(a.x, a.y);
    f.u.y = pack_bf16(a.z, a.w);
    f.u.z = pack_bf16(b.x, b.y);
    f.u.w = pack_bf16(b.z, b.w);
    return f.s;
}

// D-layout write to fp32 tile: col=16w+(lane&15), rows (lane>>4)*4+r
__device__ __forceinline__ void dwrite(float* T, int w, int lane, f4v d)
{
    int col = 16 * w + (lane & 15);
    int r0 = (lane >> 4) * 4;
    #pragma unroll
    for (int r = 0; r < 4; ++r) T[(r0 + r) * RS_ + col] = d[r];
}

// D-layout read from fp32 tile
__device__ __forceinline__ f4v dread(const float* T, int w, int lane)
{
    int col = 16 * w + (lane & 15);
    int r0 = (lane >> 4) * 4;
    f4v v;
    #pragma unroll
    for (int r = 0; r < 4; ++r) v[r] = T[(r0 + r) * RS_ + col];
    return v;
}

#define MFMA(a, b, c) __builtin_amdgcn_mfma_f32_16x16x32_bf16((a), (b), (c), 0, 0, 0)

// ================= fully fused graph layer (MFMA) ===========================
// 16 nodes/block, 256 threads = 4 waves; wave w owns col-tile w = head w.
// Passes: q, states x3, kk x3, vv x3, x, az x2, ar x2, ah x2 -> 34 MFMA/wave.
__global__ __launch_bounds__(256, 3) void k_layer(
    const float* __restrict__ hin, float* __restrict__ hout,
    const int* __restrict__ neigh, const int* __restrict__ numn,
    const float* __restrict__ nbW, const float* __restrict__ Wq,
    const float* __restrict__ Wk, const float* __restrict__ Wv,
    const float* __restrict__ Wo,
    const float* __restrict__ gWz, const float* __restrict__ gUz, const float* __restrict__ gbz,
    const float* __restrict__ gWr, const float* __restrict__ gUr, const float* __restrict__ gbr,
    const float* __restrict__ gWh, const float* __restrict__ gUh, const float* __restrict__ gbh)
{
    __shared__ __align__(16) unsigned wf0[2048];   // 8KB B-frag slot A
    __shared__ __align__(16) unsigned wf1[2048];   // 8KB B-frag slot B
    __shared__ __align__(16) float sM[3][16 * RS_];// mean -> states; sM[0] later rh
    __shared__ __align__(16) float sH[16 * RS_];   // h tile (stable all layer)
    __shared__ __align__(16) float sX[16 * RS_];   // ao -> x tile
    __shared__ int sIdx[3][256];

    int tx = threadIdx.x;
    int wv = tx >> 6;                  // wave = col-tile = head
    int lane = tx & 63;
    int row = tx >> 4;                 // gather ownership (rows 0..15)
    int cg = tx & 15, c0 = cg * 4;
    int g = blockIdx.x * 16 + row;     // node id (grid exact: 1250*16=20000)
    int b = g / N_;
    int pad = numn[b];
    const float4* hb4 = (const float4*)(hin + (size_t)b * N_ * D_);

    // ---- Ph0: stage Wq|nbW (frag order), h rows, neighbor ids ----
    stageWF(wf0, Wq, tx);
    stageWF(wf1, nbW, tx);
    *(float4*)&sH[row * RS_ + c0] = *(const float4*)&hin[(size_t)g * 64 + c0];
    #pragma unroll
    for (int t = 0; t < 3; ++t)
        sIdx[t][cg * 16 + row] = neigh[((size_t)t * BN_ + g) * K_ + cg];
    __syncthreads();                                           // B0

    // ---- Ph1: read q/nbW B-frags + h A-frags; q; gather means ----
    s8v qB0 = bfrag(wf0, 0, wv, lane), qB1 = bfrag(wf0, 1, wv, lane);
    s8v nB0 = bfrag(wf1, 0, wv, lane), nB1 = bfrag(wf1, 1, wv, lane);
    s8v hA0 = afragS(sH, lane, 0), hA1 = afragS(sH, lane, 1);

    f4v qD = {0.f, 0.f, 0.f, 0.f};
    qD = MFMA(hA0, qB0, qD);
    qD = MFMA(hA1, qB1, qD);

    #pragma unroll
    for (int t = 0; t < 3; ++t) {
        float4 s = make_float4(0.f, 0.f, 0.f, 0.f);
        int cnt = 0;
        #pragma unroll
        for (int k = 0; k < K_; ++k) {
            int idx = sIdx[t][k * 16 + row];
            if (idx != pad) {
                float4 v = hb4[(size_t)idx * 16 + cg];
                s.x += v.x; s.y += v.y; s.z += v.z; s.w += v.w;
                cnt++;
            }
        }
        float inv = 1.f / fmaxf((float)cnt, 1.f);
        *(float4*)&sM[t][row * RS_ + c0] =
            make_float4(s.x * inv, s.y * inv, s.z * inv, s.w * inv);
    }
    __syncthreads();                                           // B1

    // ---- Ph2: states = tanh(mean @ nbW), in-place sM ----
    s8v mA[3][2];
    #pragma unroll
    for (int t = 0; t < 3; ++t) {
        mA[t][0] = afragS(sM[t], lane, 0);
        mA[t][1] = afragS(sM[t], lane, 1);
    }
    __syncthreads();                                           // B2 (reads done)
    #pragma unroll
    for (int t = 0; t < 3; ++t) {
        f4v d = {0.f, 0.f, 0.f, 0.f};
        d = MFMA(mA[t][0], nB0, d);
        d = MFMA(mA[t][1], nB1, d);
        #pragma unroll
        for (int r = 0; r < 4; ++r) d[r] = tanhf(d[r]);
        dwrite(sM[t], wv, lane, d);
    }
    stageWF(wf0, Wk, tx);
    stageWF(wf1, Wv, tx);
    __syncthreads();                                           // B3

    // ---- Ph3: kk, scores, softmax, vv, ao (all D-space, lane-local) ----
    s8v kB0 = bfrag(wf0, 0, wv, lane), kB1 = bfrag(wf0, 1, wv, lane);
    s8v vB0 = bfrag(wf1, 0, wv, lane), vB1 = bfrag(wf1, 1, wv, lane);
    s8v stA[3][2];
    #pragma unroll
    for (int t = 0; t < 3; ++t) {
        stA[t][0] = afragS(sM[t], lane, 0);
        stA[t][1] = afragS(sM[t], lane, 1);
    }
    __syncthreads();                                           // B4 (reads done)

    float sc[3][4];
    #pragma unroll
    for (int t = 0; t < 3; ++t) {
        f4v kk = {0.f, 0.f, 0.f, 0.f};
        kk = MFMA(stA[t][0], kB0, kk);
        kk = MFMA(stA[t][1], kB1, kk);
        float p0 = kk[0] * qD[0], p1 = kk[1] * qD[1];
        float p2 = kk[2] * qD[2], p3 = kk[3] * qD[3];
        #pragma unroll
        for (int m = 1; m < 16; m <<= 1) {
            p0 += __shfl_xor(p0, m, 64);
            p1 += __shfl_xor(p1, m, 64);
            p2 += __shfl_xor(p2, m, 64);
            p3 += __shfl_xor(p3, m, 64);
        }
        sc[t][0] = p0 * 0.25f; sc[t][1] = p1 * 0.25f;          // / sqrt(16)
        sc[t][2] = p2 * 0.25f; sc[t][3] = p3 * 0.25f;
    }
    f4v w0v, w1v, w2v;
    #pragma unroll
    for (int r = 0; r < 4; ++r) {
        float p0 = sc[0][r], p1 = sc[1][r], p2 = sc[2][r];
        float mx = fmaxf(p0, fmaxf(p1, p2));
        float e0 = expf(p0 - mx), e1 = expf(p1 - mx), e2 = expf(p2 - mx);
        float inv = 1.f / (e0 + e1 + e2);
        w0v[r] = e0 * inv; w1v[r] = e1 * inv; w2v[r] = e2 * inv;
    }
    f4v ao = {0.f, 0.f, 0.f, 0.f};
    {
        f4v vv0 = {0.f,0.f,0.f,0.f}, vv1 = {0.f,0.f,0.f,0.f}, vv2 = {0.f,0.f,0.f,0.f};
        vv0 = MFMA(stA[0][0], vB0, vv0); vv0 = MFMA(stA[0][1], vB1, vv0);
        vv1 = MFMA(stA[1][0], vB0, vv1); vv1 = MFMA(stA[1][1], vB1, vv1);
        vv2 = MFMA(stA[2][0], vB0, vv2); vv2 = MFMA(stA[2][1], vB1, vv2);
        #pragma unroll
        for (int r = 0; r < 4; ++r)
            ao[r] = w0v[r] * vv0[r] + w1v[r] * vv1[r] + w2v[r] * vv2[r];
    }
    dwrite(sX, wv, lane, ao);
    stageWF(wf0, Wo, tx);
    stageWF(wf1, gWz, tx);
    __syncthreads();                                           // B5

    // ---- Ph4: x = tanh(ao @ Wo), in-place sX ----
    s8v oB0 = bfrag(wf0, 0, wv, lane), oB1 = bfrag(wf0, 1, wv, lane);
    s8v zB0 = bfrag(wf1, 0, wv, lane), zB1 = bfrag(wf1, 1, wv, lane);
    s8v aoA0 = afragS(sX, lane, 0), aoA1 = afragS(sX, lane, 1);
    __syncthreads();                                           // B6 (reads done)
    {
        f4v xd = {0.f, 0.f, 0.f, 0.f};
        xd = MFMA(aoA0, oB0, xd);
        xd = MFMA(aoA1, oB1, xd);
        #pragma unroll
        for (int r = 0; r < 4; ++r) xd[r] = tanhf(xd[r]);
        dwrite(sX, wv, lane, xd);
    }
    stageWF(wf0, gUz, tx);
    stageWF(wf1, gWr, tx);
    __syncthreads();                                           // B7

    // ---- Ph5: az = x@gWz + h@gUz ; ar(part) = x@gWr ----
    s8v xA0 = afragS(sX, lane, 0), xA1 = afragS(sX, lane, 1);
    s8v uzB0 = bfrag(wf0, 0, wv, lane), uzB1 = bfrag(wf0, 1, wv, lane);
    s8v rB0 = bfrag(wf1, 0, wv, lane), rB1 = bfrag(wf1, 1, wv, lane);
    __syncthreads();                                           // B8 (reads done)
    f4v az = {0.f, 0.f, 0.f, 0.f}, ar = {0.f, 0.f, 0.f, 0.f};
    az = MFMA(xA0, zB0, az);  az = MFMA(xA1, zB1, az);
    az = MFMA(hA0, uzB0, az); az = MFMA(hA1, uzB1, az);
    ar = MFMA(xA0, rB0, ar);  ar = MFMA(xA1, rB1, ar);
    stageWF(wf0, gUr, tx);
    stageWF(wf1, gWh, tx);
    __syncthreads();                                           // B9

    // ---- Ph6: ar += h@gUr ; z,r ; rh -> sM[0] ; ah(part) = x@gWh ----
    s8v urB0 = bfrag(wf0, 0, wv, lane), urB1 = bfrag(wf0, 1, wv, lane);
    s8v whB0 = bfrag(wf1, 0, wv, lane), whB1 = bfrag(wf1, 1, wv, lane);
    f4v hD = dread(sH, wv, lane);
    __syncthreads();                                           // B10 (reads done)
    ar = MFMA(hA0, urB0, ar);
    ar = MFMA(hA1, urB1, ar);
    int col = 16 * wv + (lane & 15);
    float bzv = gbz[col], brv = gbr[col];
    f4v zg, rh;
    #pragma unroll
    for (int r = 0; r < 4; ++r) {
        zg[r] = 1.f / (1.f + expf(-(az[r] + bzv)));
        float rr = 1.f / (1.f + expf(-(ar[r] + brv)));
        rh[r] = rr * hD[r];
    }
    dwrite(sM[0], wv, lane, rh);
    f4v ah = {0.f, 0.f, 0.f, 0.f};
    ah = MFMA(xA0, whB0, ah);
    ah = MFMA(xA1, whB1, ah);
    stageWF(wf0, gUh, tx);
    __syncthreads();                                           // B11

    // ---- Ph7: ah += rh@gUh ; h' -> global ----
    s8v uhB0 = bfrag(wf0, 0, wv, lane), uhB1 = bfrag(wf0, 1, wv, lane);
    s8v rhA0 = afragS(sM[0], lane, 0), rhA1 = afragS(sM[0], lane, 1);
    ah = MFMA(rhA0, uhB0, ah);
    ah = MFMA(rhA1, uhB1, ah);
    float bhv = gbh[col];
    int base = blockIdx.x * 16;
    int r0 = (lane >> 4) * 4;
    #pragma unroll
    for (int r = 0; r < 4; ++r) {
        float hh = tanhf(ah[r] + bhv);
        float o = (1.f - zg[r]) * hD[r] + zg[r] * hh;
        hout[(size_t)(base + r0 + r) * 64 + col] = o;
    }
}

// ---------------- edge projection ------------------------------------------
__global__ __launch_bounds__(256) void k_edgeproj(
    const float* __restrict__ h, const float* __restrict__ W1,
    float* __restrict__ P)
{
    int wave = threadIdx.x >> 6;
    int lane = threadIdx.x & 63;
    int node = blockIdx.x * 4 + wave;      // < 20000

    float hval = h[(size_t)node * D_ + lane];
    const float* wp = (lane < 32) ? (W1 + lane) : (W1 + 64 * 32 + (lane - 32));
    float acc = 0.f;
    #pragma unroll 8
    for (int i = 0; i < D_; ++i)
        acc = fmaf(__shfl(hval, i, 64), wp[i * 32], acc);
    P[(size_t)node * D_ + lane] = acc;
}

// ---------------- edge decoder (light) --------------------------------------
__global__ __launch_bounds__(256) void k_decoder2(
    const float* __restrict__ P, const int* __restrict__ adj,
    const float* __restrict__ b1, const float* __restrict__ W2,
    const float* __restrict__ b2, const int* __restrict__ num_nodes,
    float* __restrict__ nw)
{
    int half = threadIdx.x >> 5;   // 0..7
    int j    = threadIdx.x & 31;
    float bias = b1[j], w2 = W2[j], b2v = b2[0];

    #pragma unroll 1
    for (int p = 0; p < 16; ++p) {
        int e = blockIdx.x * 128 + p * 8 + half;  // edge id < 320000
        int node = e >> 4;                        // b*N+n
        int b = node / N_;
        int a = adj[e];
        int pad = num_nodes[b];
        float own = P[(size_t)node * D_ + j];
        bool pd = (a == pad);
        float nbr = pd ? 0.f : P[((size_t)b * N_ + a) * D_ + 32 + j];
        float am = pd ? 0.f : 1.f;
        float t = tanhf(bias + am * own + nbr);
        float part = t * w2;
        #pragma unroll
        for (int m = 1; m < 32; m <<= 1) part += __shfl_xor(part, m, 64);
        if (j == 0) nw[e] = part + b2v;
    }
}

// ---------------- dual vars (per node scalar) + dual_demand -----------------
__global__ __launch_bounds__(256) void k_dualvars(
    const float* __restrict__ h, const float* __restrict__ W1,
    const float* __restrict__ b1, const float* __restrict__ W2,
    const float* __restrict__ b2, const float* __restrict__ demands,
    const int* __restrict__ num_nodes,
    float* __restrict__ dv, float* __restrict__ acc_out)
{
    __shared__ float sW1[D_ * 32];
    __shared__ float sW2[32];
    __shared__ float sPart[8];
    for (int i = threadIdx.x; i < D_ * 32; i += 256) sW1[i] = W1[i];
    if (threadIdx.x < 32) sW2[threadIdx.x] = W2[threadIdx.x];
    __syncthreads();

    int half = threadIdx.x >> 5;
    int j    = threadIdx.x & 31;
    int b = (blockIdx.x * 40) / N_;
    float bias = b1[j], b2v = b2[0];
    float local = 0.f;

    #pragma unroll 1
    for (int p = 0; p < 5; ++p) {
        int node = blockIdx.x * 40 + p * 8 + half;    // < 20000
        const float* hp = h + (size_t)node * D_;
        float h0 = hp[j], h1 = hp[j + 32];
        float acc = bias;
        #pragma unroll 8
        for (int i = 0; i < 32; ++i) {
            acc = fmaf(__shfl(h0, i, 32), sW1[i * 32 + j],        acc);
            acc = fmaf(__shfl(h1, i, 32), sW1[(i + 32) * 32 + j], acc);
        }
        float t = tanhf(acc);
        float part = t * sW2[j];
        #pragma unroll
        for (int m = 1; m < 32; m <<= 1) part += __shfl_xor(part, m, 64);
        if (j == 0) {
            float v = part + b2v;
            dv[node] = v;
            local += v * demands[node];
        }
    }
    if (j == 0) sPart[half] = local;
    __syncthreads();
    if (threadIdx.x == 0) {
        float s = 0.f;
        #pragma unroll
        for (int i = 0; i < 8; ++i) s += sPart[i];
        atomicAdd(&acc_out[(b * 3 + 2) * 16], s);
    }
}

// ---------------- dest softmax over permuted groups -------------------------
__global__ void k_dest(
    const float* __restrict__ nw, const int* __restrict__ in_idx,
    const int* __restrict__ inv_adj, const int* __restrict__ num_nodes,
    float* __restrict__ dest)
{
    int t = blockIdx.x * 256 + threadIdx.x;
    if (t >= BN_) return;
    int b = t / N_;
    int pad = num_nodes[b];
    float vals[K_]; float mx = -INFINITY;
    #pragma unroll
    for (int k = 0; k < K_; ++k) {
        int jj = in_idx[(size_t)t * K_ + k];
        float g = nw[(size_t)b * NK_ + jj];
        float im = (inv_adj[(size_t)t * K_ + k] == pad) ? 1.f : 0.f;
        float v = g - BIG_ * im;
        vals[k] = v; mx = fmaxf(mx, v);
    }
    float s = 0.f;
    #pragma unroll
    for (int k = 0; k < K_; ++k) { vals[k] = expf(vals[k] - mx); s += vals[k]; }
    float invs = 1.f / s;
    #pragma unroll
    for (int k = 0; k < K_; ++k) dest[(size_t)t * K_ + k] = vals[k] * invs;
}

// ---------------- normalized_weights ----------------------------------------
__global__ void k_normw(
    const float* __restrict__ nw, const float* __restrict__ dest,
    const int* __restrict__ rev, const int* __restrict__ adj,
    const int* __restrict__ num_nodes,
    float* __restrict__ normw)
{
    int t = blockIdx.x * 256 + threadIdx.x;
    if (t >= BN_) return;
    int b = t / N_;
    int pad = num_nodes[b];
    float vals[K_]; float mx = -INFINITY;
    #pragma unroll
    for (int k = 0; k < K_; ++k) {
        size_t e = (size_t)t * K_ + k;
        float v = nw[e] * dest[(size_t)b * NK_ + rev[e]];
        float m = (adj[e] == pad) ? 1.f : 0.f;
        v -= BIG_ * m;
        vals[k] = v; mx = fmaxf(mx, v);
    }
    float s = 0.f;
    #pragma unroll
    for (int k = 0; k < K_; ++k) { vals[k] = expf(vals[k] - mx); s += vals[k]; }
    float invs = 1.f / s;
    #pragma unroll
    for (int k = 0; k < K_; ++k)
        normw[(size_t)t * K_ + k] = vals[k] * invs;
}

// ---------------- flow prep: supply, iteration weights + source nodes -------
__global__ void k_prep(
    const float* __restrict__ normw, const int* __restrict__ in_idx,
    const int* __restrict__ inv_adj, const int* __restrict__ num_nodes,
    const float* __restrict__ demands,
    float* __restrict__ supply, float* __restrict__ wgt, int* __restrict__ srcn,
    float* __restrict__ tot0)
{
    int t = blockIdx.x * 256 + threadIdx.x;
    if (t >= BN_) return;
    int b = t / N_;
    int pad = num_nodes[b];
    float sup = fmaxf(-demands[t], 0.f);
    supply[t] = sup;
    tot0[t] = sup;
    #pragma unroll
    for (int k = 0; k < K_; ++k) {
        size_t e = (size_t)t * K_ + k;
        int j = in_idx[e];
        bool valid = (inv_adj[e] != pad);
        wgt[e] = valid ? normw[(size_t)b * NK_ + j] : 0.f;
        srcn[e] = b * N_ + (j >> 4);
    }
}

// ---------------- one tot-space flow step (80KB state) ----------------------
__global__ void k_flowT(
    const float* __restrict__ totIn, const float* __restrict__ wgt,
    const int* __restrict__ srcn, const float* __restrict__ supply,
    float* __restrict__ totOut)
{
    int t = blockIdx.x * 256 + threadIdx.x;
    if (t >= BN_) return;
    float s = supply[t];
    #pragma unroll
    for (int k = 0; k < K_; ++k) {
        size_t e = (size_t)t * K_ + k;
        s = fmaf(wgt[e], totIn[srcn[e]], s);
    }
    totOut[t] = s;
}

// ---------------- dual iterations + both cost reductions --------------------
__global__ __launch_bounds__(256) void k_dualred(
    const float* __restrict__ el, const float* __restrict__ dv,
    const int* __restrict__ adj, const int* __restrict__ num_nodes,
    const float* __restrict__ normw, const float* __restrict__ tot10,
    float* __restrict__ acc_out)
{
    int b = blockIdx.y;
    int ein = blockIdx.x * 256 + threadIdx.x;
    float c0 = 0.f, c1 = 0.f;
    if (ein < NK_) {
        size_t e = (size_t)b * NK_ + ein;
        int pad = num_nodes[b];
        int node = b * N_ + (ein >> 4);
        int a = adj[e];
        float am = (a == pad) ? 0.f : 1.f;
        float dtr = (a == pad) ? 0.f : dv[(size_t)b * N_ + a];
        float d = dtr - am * dv[node];
        float l = el[e];
        float f = 0.f, ac = 0.f;
        #pragma unroll
        for (int it = 0; it < 10; ++it) {
            float g = 2.f * l * f + d;
            ac = 0.9f * ac + 0.01f * g;
            f = fmaxf(f - ac, 0.f) * am;
        }
        float fl = normw[e] * tot10[node];
        c0 = l * fl * fl;          // flow_cost term
        c1 = l * f * f + d * f;    // dual flow term
    }
    #pragma unroll
    for (int m = 1; m < 64; m <<= 1) { c0 += __shfl_xor(c0, m, 64); c1 += __shfl_xor(c1, m, 64); }
    __shared__ float s0[4], s1[4];
    int wave = threadIdx.x >> 6, lane = threadIdx.x & 63;
    if (lane == 0) { s0[wave] = c0; s1[wave] = c1; }
    __syncthreads();
    if (threadIdx.x == 0) {
        atomicAdd(&acc_out[(b * 3 + 0) * 16], s0[0] + s0[1] + s0[2] + s0[3]);
        atomicAdd(&acc_out[(b * 3 + 1) * 16], s1[0] + s1[1] + s1[2] + s1[3]);
    }
}

// ---------------- finalize --------------------------------------------------
__global__ void k_final(const float* __restrict__ acc, float* __restrict__ out) {
    int b = threadIdx.x;
    if (b < B_)
        out[b] = acc[(b * 3 + 0) * 16] - acc[(b * 3 + 1) * 16] + acc[(b * 3 + 2) * 16];
}

extern "C" void kernel_launch(void* const* d_in, const int* in_sizes, int n_in,
                              void* d_out, int out_size, void* d_ws, size_t ws_size,
                              hipStream_t stream)
{
    const float* demands = (const float*)d_in[0];
    const float* feat    = (const float*)d_in[1];
    const float* el      = (const float*)d_in[2];
    const float* embed   = (const float*)d_in[3];
    const float* encW    = (const float*)d_in[4];
    const float* encb    = (const float*)d_in[5];
    const float* nbW     = (const float*)d_in[6];
    const float* Wq      = (const float*)d_in[7];
    const float* Wk      = (const float*)d_in[8];
    const float* Wv      = (const float*)d_in[9];
    const float* Wo      = (const float*)d_in[10];
    const float* gWz     = (const float*)d_in[11];
    const float* gUz     = (const float*)d_in[12];
    const float* gbz     = (const float*)d_in[13];
    const float* gWr     = (const float*)d_in[14];
    const float* gUr     = (const float*)d_in[15];
    const float* gbr     = (const float*)d_in[16];
    const float* gWh     = (const float*)d_in[17];
    const float* gUh     = (const float*)d_in[18];
    const float* gbh     = (const float*)d_in[19];
    const float* decW1   = (const float*)d_in[20];
    const float* decb1   = (const float*)d_in[21];
    const float* decW2   = (const float*)d_in[22];
    const float* decb2   = (const float*)d_in[23];
    const float* dualW1  = (const float*)d_in[24];
    const float* dualb1  = (const float*)d_in[25];
    const float* dualW2  = (const float*)d_in[26];
    const float* dualb2  = (const float*)d_in[27];
    const int* adj       = (const int*)d_in[28];
    const int* invadj    = (const int*)d_in[29];
    const int* neigh     = (const int*)d_in[30];
    const int* inidx     = (const int*)d_in[31];
    const int* revidx    = (const int*)d_in[32];
    const int* numn      = (const int*)d_in[33];

    // workspace (floats), ~17MB
    float* ws     = (float*)d_ws;
    float* h0     = ws;                   // 1,280,000
    float* h1     = ws + 1280000;         // 1,280,000 (ping-pong; P after layers)
    float* nw     = ws + 2560000;         // 320,000
    float* dest   = ws + 2880000;         // 320,000
    float* normw  = ws + 3200000;         // 320,000
    float* wgt    = ws + 3520000;         // 320,000
    int*   srcn   = (int*)(ws + 3840000); // 320,000 ints
    float* totA   = ws + 4160000;         // 20,000
    float* totB   = ws + 4180000;         // 20,000
    float* supply = ws + 4200000;         // 20,000
    float* dv     = ws + 4220000;         // 20,000
    float* P      = h1;                   // reuse (h1 dead after layer 1)
    float* acc    = ws + 4240000;         // 192

    k_zero<<<1, 256, 0, stream>>>(acc);
    k_encode<<<BN_ / 4, 256, 0, stream>>>(embed, feat, encW, encb, h0);

    // layer 0: h0 -> h1 ; layer 1: h1 -> h0  (gathers must read pre-layer h)
    k_layer<<<BN_ / 16, 256, 0, stream>>>(h0, h1, neigh, numn, nbW, Wq, Wk, Wv, Wo,
                                          gWz, gUz, gbz, gWr, gUr, gbr, gWh, gUh, gbh);
    k_layer<<<BN_ / 16, 256, 0, stream>>>(h1, h0, neigh, numn, nbW, Wq, Wk, Wv, Wo,
                                          gWz, gUz, gbz, gWr, gUr, gbr, gWh, gUh, gbh);
    float* h = h0;

    k_edgeproj<<<BN_ / 4, 256, 0, stream>>>(h, decW1, P);
    k_decoder2<<<(B_ * NK_) / 128, 256, 0, stream>>>(P, adj, decb1, decW2, decb2, numn, nw);
    k_dualvars<<<BN_ / 40, 256, 0, stream>>>(h, dualW1, dualb1, dualW2, dualb2, demands, numn, dv, acc);
    k_dest<<<(BN_ + 255) / 256, 256, 0, stream>>>(nw, inidx, invadj, numn, dest);
    k_normw<<<(BN_ + 255) / 256, 256, 0, stream>>>(nw, dest, revidx, adj, numn, normw);
    k_prep<<<(BN_ + 255) / 256, 256, 0, stream>>>(normw, inidx, invadj, numn, demands,
                                                  supply, wgt, srcn, totA);

    float* cur = totA; float* nxt = totB;
    for (int it = 0; it < 10; ++it) {
        k_flowT<<<(BN_ + 255) / 256, 256, 0, stream>>>(cur, wgt, srcn, supply, nxt);
        float* tmp = cur; cur = nxt; nxt = tmp;
    }

    dim3 gred((NK_ + 255) / 256, B_);
    k_dualred<<<gred, 256, 0, stream>>>(el, dv, adj, numn, normw, cur, acc);
    k_final<<<1, 64, 0, stream>>>(acc, (float*)d_out);
}